// Round 7
// baseline (4097.411 us; speedup 1.0000x reference)
//
#include <hip/hip_runtime.h>
#include <hip/hip_bf16.h>
#include <hip/hip_fp16.h>
#include <hip/hip_cooperative_groups.h>

namespace cg = cooperative_groups;

#define NORM_EPS_F 1e-6f
#define COS_EPS_F  1e-8f
#define BK   512       // vertices per fine bucket
#define BKSH 9
#define NBGMAX 2048    // max fine buckets per pass
#define CHF1 2048      // faces per bucket_F1 block
#define CHL1 4096      // nnz per bucket_L1 block
#define K2   32        // blocks per coarse bucket in stage 2
#define NOCT 8         // windows for L2-phased gathers

__device__ __forceinline__ void atomAddF(float* p, float v) {
    unsafeAtomicAdd(p, v);   // hardware global_atomic_add_f32
}

__device__ __forceinline__ unsigned packh2(float a, float b) {
    return (unsigned)__half_as_ushort(__float2half(a)) |
           ((unsigned)__half_as_ushort(__float2half(b)) << 16);
}
__device__ __forceinline__ float unpL(unsigned u) {
    return __half2float(__ushort_as_half((unsigned short)(u & 0xffff)));
}
__device__ __forceinline__ float unpH(unsigned u) {
    return __half2float(__ushort_as_half((unsigned short)(u >> 16)));
}

template<int NV>
__device__ __forceinline__ void blockReduceAtomicN(float (&v)[NV], float* dst) {
    #pragma unroll
    for (int off = 32; off > 0; off >>= 1) {
        #pragma unroll
        for (int k = 0; k < NV; ++k) v[k] += __shfl_down(v[k], off, 64);
    }
    __shared__ float red[4][NV];
    int wave = threadIdx.x >> 6, lane = threadIdx.x & 63;
    if (lane == 0) {
        #pragma unroll
        for (int k = 0; k < NV; ++k) red[wave][k] = v[k];
    }
    __syncthreads();
    if (threadIdx.x == 0) {
        float s[NV];
        #pragma unroll
        for (int k = 0; k < NV; ++k) s[k] = 0.f;
        for (int w = 0; w < 4; ++w)
            #pragma unroll
            for (int k = 0; k < NV; ++k) s[k] += red[w][k];
        #pragma unroll
        for (int k = 0; k < NV; ++k) atomAddF(&dst[k], s[k]);
    }
}

// ======================= FAST PATH =======================

__global__ void __launch_bounds__(256) pack_l1_kernel(
    const float* __restrict__ Vr, const float* __restrict__ Vg,
    float4* __restrict__ Vp, float* __restrict__ accum, int N)
{
    int i = blockIdx.x * blockDim.x + threadIdx.x;
    float l1[1] = {0.f};
    if (i < N) {
        float rx = Vr[3 * i], ry = Vr[3 * i + 1], rz = Vr[3 * i + 2];
        float gx = Vg[3 * i], gy = Vg[3 * i + 1], gz = Vg[3 * i + 2];
        Vp[2 * i]     = make_float4(rx, ry, rz, 0.f);
        Vp[2 * i + 1] = make_float4(gx, gy, gz, 0.f);
        l1[0] = fabsf(rx - gx) + fabsf(ry - gy) + fabsf(rz - gz);
    }
    blockReduceAtomicN<1>(l1, &accum[0]);
}

// Face normals (both meshes) -> fp16-packed uint4 (16 B/face). 2 faces/thread.
__global__ void __launch_bounds__(256) fn_kernel(
    const float4* __restrict__ Vp, const int* __restrict__ faces,
    uint4* __restrict__ FNH, int F)
{
    int half = (F + 1) >> 1;
    int t = blockIdx.x * blockDim.x + threadIdx.x;
    if (t >= half) return;
    int fi[2] = {t, t + half};
    int n = (fi[1] < F) ? 2 : 1;
    int idx[2][3];
    #pragma unroll
    for (int k = 0; k < 2; ++k) if (k < n) {
        idx[k][0] = faces[3 * fi[k]];
        idx[k][1] = faces[3 * fi[k] + 1];
        idx[k][2] = faces[3 * fi[k] + 2];
    }
    float4 r0[2], r1[2], r2[2], g0[2], g1[2], g2[2];
    #pragma unroll
    for (int k = 0; k < 2; ++k) if (k < n) {
        r0[k] = Vp[2 * idx[k][0]]; g0[k] = Vp[2 * idx[k][0] + 1];
        r1[k] = Vp[2 * idx[k][1]]; g1[k] = Vp[2 * idx[k][1] + 1];
        r2[k] = Vp[2 * idx[k][2]]; g2[k] = Vp[2 * idx[k][2] + 1];
    }
    #pragma unroll
    for (int k = 0; k < 2; ++k) if (k < n) {
        float ax = r1[k].x - r0[k].x, ay = r1[k].y - r0[k].y, az = r1[k].z - r0[k].z;
        float bx = r2[k].x - r0[k].x, by = r2[k].y - r0[k].y, bz = r2[k].z - r0[k].z;
        float nrx = ay * bz - az * by, nry = az * bx - ax * bz, nrz = ax * by - ay * bx;
        ax = g1[k].x - g0[k].x; ay = g1[k].y - g0[k].y; az = g1[k].z - g0[k].z;
        bx = g2[k].x - g0[k].x; by = g2[k].y - g0[k].y; bz = g2[k].z - g0[k].z;
        float ngx = ay * bz - az * by, ngy = az * bx - ax * bz, ngz = ax * by - ay * bx;
        FNH[fi[k]] = make_uint4(packh2(nrx, nry), packh2(nrz, ngx), packh2(ngy, ngz), 0u);
    }
}

// ---- Stage 1 (coarse): line-granular scatter runs ----

// recC byte = (fineRow<<3) | faceOctant
__global__ void __launch_bounds__(256) bucket_F1(
    const int* __restrict__ faces, int* __restrict__ cntC,
    unsigned* __restrict__ recA, unsigned char* __restrict__ recC,
    int capC, int F, int b0, int bcnt, int chunk, int fsh)
{
    __shared__ int hist[64];
    int f0 = blockIdx.x * chunk, f1 = min(f0 + chunk, F);
    if (threadIdx.x < 64) hist[threadIdx.x] = 0;
    __syncthreads();
    for (int f = f0 + threadIdx.x; f < f1; f += 256) {
        #pragma unroll
        for (int c = 0; c < 3; ++c) {
            unsigned fb = ((unsigned)faces[3 * f + c] >> BKSH) - (unsigned)b0;
            if (fb < (unsigned)bcnt) atomicAdd(&hist[fb >> 5], 1);
        }
    }
    __syncthreads();
    if (threadIdx.x < 64) {
        int h = hist[threadIdx.x];
        if (h) hist[threadIdx.x] = atomicAdd(&cntC[threadIdx.x], h);
    }
    __syncthreads();
    for (int f = f0 + threadIdx.x; f < f1; f += 256) {
        #pragma unroll
        for (int c = 0; c < 3; ++c) {
            int v = faces[3 * f + c];
            unsigned fb = ((unsigned)v >> BKSH) - (unsigned)b0;
            if (fb < (unsigned)bcnt) {
                int pos = atomicAdd(&hist[fb >> 5], 1);
                if (pos < capC) {
                    size_t idx = (size_t)(fb >> 5) * capC + pos;
                    recA[idx] = ((unsigned)f << BKSH) | ((unsigned)v & (BK - 1));
                    recC[idx] = (unsigned char)(((fb & 31) << 3) | ((unsigned)f >> fsh));
                }
            }
        }
    }
}

// recC byte = (fineRow<<3) | colOctant
__global__ void __launch_bounds__(256) bucket_L1(
    const int* __restrict__ rows, const int* __restrict__ cols,
    const float* __restrict__ vals, int* __restrict__ cntC,
    int2* __restrict__ recA, unsigned char* __restrict__ recC,
    int capC, int nnz, int b0, int bcnt, int chunk, int octsh)
{
    __shared__ int hist[64];
    int i0 = blockIdx.x * chunk, i1 = min(i0 + chunk, nnz);
    if (threadIdx.x < 64) hist[threadIdx.x] = 0;
    __syncthreads();
    for (int i = i0 + threadIdx.x; i < i1; i += 256) {
        unsigned fb = ((unsigned)rows[i] >> BKSH) - (unsigned)b0;
        if (fb < (unsigned)bcnt) atomicAdd(&hist[fb >> 5], 1);
    }
    __syncthreads();
    if (threadIdx.x < 64) {
        int h = hist[threadIdx.x];
        if (h) hist[threadIdx.x] = atomicAdd(&cntC[threadIdx.x], h);
    }
    __syncthreads();
    for (int i = i0 + threadIdx.x; i < i1; i += 256) {
        int r = rows[i];
        unsigned fb = ((unsigned)r >> BKSH) - (unsigned)b0;
        if (fb < (unsigned)bcnt) {
            int pos = atomicAdd(&hist[fb >> 5], 1);
            if (pos < capC) {
                size_t idx = (size_t)(fb >> 5) * capC + pos;
                unsigned c = (unsigned)cols[i];
                recA[idx] = make_int2(
                    (int)((c << BKSH) | ((unsigned)r & (BK - 1))),
                    __float_as_int(vals[i]));
                recC[idx] = (unsigned char)(((fb & 31) << 3) | (c >> octsh));
            }
        }
    }
}

// ---- Stage 2 (fine, 256 keys = fine<<3|oct; L2-resident scatter) ----

__global__ void __launch_bounds__(256) bucket_F2(
    const int* __restrict__ cntC, const unsigned* __restrict__ recA,
    const unsigned char* __restrict__ recC, int capC,
    int* __restrict__ cntFine, unsigned* __restrict__ fine, int capFS)
{
    __shared__ int hist[256];
    int c = blockIdx.x;
    int K = gridDim.y, k = blockIdx.y;
    int ch = (capC + K - 1) / K;
    int n = min(cntC[c], capC);
    int i0 = k * ch, i1 = min(i0 + ch, n);
    hist[threadIdx.x] = 0;
    __syncthreads();
    const size_t base = (size_t)c * capC;
    for (int i = i0 + threadIdx.x; i < i1; i += 256)
        atomicAdd(&hist[recC[base + i]], 1);
    __syncthreads();
    {
        int h = hist[threadIdx.x];
        if (h) hist[threadIdx.x] = atomicAdd(&cntFine[(c << 8) + threadIdx.x], h);
    }
    __syncthreads();
    for (int i = i0 + threadIdx.x; i < i1; i += 256) {
        int fic = recC[base + i];
        int pos = atomicAdd(&hist[fic], 1);
        if (pos < capFS)
            fine[(size_t)((c << 8) + fic) * capFS + pos] = recA[base + i];
    }
}

__global__ void __launch_bounds__(256) bucket_L2(
    const int* __restrict__ cntC, const int2* __restrict__ recA,
    const unsigned char* __restrict__ recC, int capC,
    int* __restrict__ cntFine, int2* __restrict__ fine, int capS)
{
    __shared__ int hist[256];
    int c = blockIdx.x;
    int K = gridDim.y, k = blockIdx.y;
    int ch = (capC + K - 1) / K;
    int n = min(cntC[c], capC);
    int i0 = k * ch, i1 = min(i0 + ch, n);
    hist[threadIdx.x] = 0;
    __syncthreads();
    const size_t base = (size_t)c * capC;
    for (int i = i0 + threadIdx.x; i < i1; i += 256)
        atomicAdd(&hist[recC[base + i]], 1);
    __syncthreads();
    {
        int h = hist[threadIdx.x];
        if (h) hist[threadIdx.x] = atomicAdd(&cntFine[(c << 8) + threadIdx.x], h);
    }
    __syncthreads();
    for (int i = i0 + threadIdx.x; i < i1; i += 256) {
        int fic = recC[base + i];
        int pos = atomicAdd(&hist[fic], 1);
        if (pos < capS)
            fine[(size_t)((c << 8) + fic) * capS + pos] = recA[base + i];
    }
}

// ---- Normals accumulate: shared body ----

__device__ __forceinline__ void normals_accum_oct(
    const uint4* __restrict__ FNH,
    const unsigned* __restrict__ rec, int n,
    float* vnr, float* vng)
{
    int i = threadIdx.x;
    for (; i + 256 < n; i += 512) {
        unsigned rc0 = rec[i], rc1 = rec[i + 256];
        uint4 u0 = FNH[rc0 >> BKSH];
        uint4 u1 = FNH[rc1 >> BKSH];
        int lv0 = rc0 & (BK - 1), lv1 = rc1 & (BK - 1);
        atomicAdd(&vnr[3 * lv0 + 0], unpL(u0.x));
        atomicAdd(&vnr[3 * lv0 + 1], unpH(u0.x));
        atomicAdd(&vnr[3 * lv0 + 2], unpL(u0.y));
        atomicAdd(&vng[3 * lv0 + 0], unpH(u0.y));
        atomicAdd(&vng[3 * lv0 + 1], unpL(u0.z));
        atomicAdd(&vng[3 * lv0 + 2], unpH(u0.z));
        atomicAdd(&vnr[3 * lv1 + 0], unpL(u1.x));
        atomicAdd(&vnr[3 * lv1 + 1], unpH(u1.x));
        atomicAdd(&vnr[3 * lv1 + 2], unpL(u1.y));
        atomicAdd(&vng[3 * lv1 + 0], unpH(u1.y));
        atomicAdd(&vng[3 * lv1 + 1], unpL(u1.z));
        atomicAdd(&vng[3 * lv1 + 2], unpH(u1.z));
    }
    for (; i < n; i += 256) {
        unsigned rc = rec[i];
        uint4 u = FNH[rc >> BKSH];
        int lv = rc & (BK - 1);
        atomicAdd(&vnr[3 * lv + 0], unpL(u.x));
        atomicAdd(&vnr[3 * lv + 1], unpH(u.x));
        atomicAdd(&vnr[3 * lv + 2], unpL(u.y));
        atomicAdd(&vng[3 * lv + 0], unpH(u.y));
        atomicAdd(&vng[3 * lv + 1], unpL(u.z));
        atomicAdd(&vng[3 * lv + 2], unpH(u.z));
    }
}

__device__ __forceinline__ void normals_epilogue(
    const float* vnr, const float* vng,
    float* accum, int N, int b0, int g)
{
    float ln[1] = {0.f};
    for (int lv = threadIdx.x; lv < BK; lv += blockDim.x) {
        int gv = ((b0 + g) << BKSH) + lv;
        if (gv < N) {
            float ax = vnr[3 * lv], ay = vnr[3 * lv + 1], az = vnr[3 * lv + 2];
            float bx = vng[3 * lv], by = vng[3 * lv + 1], bz = vng[3 * lv + 2];
            float na = sqrtf(ax * ax + ay * ay + az * az);
            float nb = sqrtf(bx * bx + by * by + bz * bz);
            float ia = 1.0f / fmaxf(na, NORM_EPS_F);
            float ib = 1.0f / fmaxf(nb, NORM_EPS_F);
            ax *= ia; ay *= ia; az *= ia;
            bx *= ib; by *= ib; bz *= ib;
            float dot = ax * bx + ay * by + az * bz;
            float nna = sqrtf(ax * ax + ay * ay + az * az);
            float nnb = sqrtf(bx * bx + by * by + bz * bz);
            float cosn = dot / (fmaxf(nna, COS_EPS_F) * fmaxf(nnb, COS_EPS_F));
            if (isnan(cosn)) cosn = 1.0f;
            ln[0] += 1.0f - cosn;
        }
    }
    blockReduceAtomicN<1>(ln, &accum[1]);
}

// Cooperative: grid-wide sync between face-octant windows (4 MB FNH each).
__global__ void __launch_bounds__(256) accum_normals_coop(
    const uint4* __restrict__ FNH,
    const int* __restrict__ cntFine, const unsigned* __restrict__ recF, int capFS,
    float* __restrict__ accum, int N, int b0)
{
    __shared__ float vnr[3 * BK];
    __shared__ float vng[3 * BK];
    int g = blockIdx.x;
    for (int i = threadIdx.x; i < 3 * BK; i += blockDim.x) { vnr[i] = 0.f; vng[i] = 0.f; }
    __syncthreads();
    for (int oct = 0; oct < NOCT; ++oct) {
        if (oct) cg::this_grid().sync();
        const unsigned* rec = recF + ((size_t)g * NOCT + oct) * capFS;
        int n = min(cntFine[g * NOCT + oct], capFS);
        normals_accum_oct(FNH, rec, n, vnr, vng);
    }
    __syncthreads();
    normals_epilogue(vnr, vng, accum, N, b0, g);
}

// Legacy (non-coop) normals: same layout, no grid sync; use_fn=0 recomputes.
__global__ void __launch_bounds__(256) accum_normals_legacy(
    const float4* __restrict__ Vp, const uint4* __restrict__ FNH,
    const int* __restrict__ faces,
    const int* __restrict__ cntFine, const unsigned* __restrict__ recF, int capFS,
    float* __restrict__ accum, int N, int b0, int use_fn)
{
    __shared__ float vnr[3 * BK];
    __shared__ float vng[3 * BK];
    int g = blockIdx.x;
    for (int i = threadIdx.x; i < 3 * BK; i += blockDim.x) { vnr[i] = 0.f; vng[i] = 0.f; }
    __syncthreads();
    for (int oct = 0; oct < NOCT; ++oct) {
        const unsigned* rec = recF + ((size_t)g * NOCT + oct) * capFS;
        int n = min(cntFine[g * NOCT + oct], capFS);
        if (use_fn) {
            normals_accum_oct(FNH, rec, n, vnr, vng);
        } else {
            for (int i = threadIdx.x; i < n; i += 256) {
                unsigned rc = rec[i];
                int lv = rc & (BK - 1);
                int f  = rc >> BKSH;
                int i0 = faces[3 * f], i1 = faces[3 * f + 1], i2 = faces[3 * f + 2];
                float4 r0 = Vp[2 * i0], r1 = Vp[2 * i1], r2 = Vp[2 * i2];
                float4 g0 = Vp[2 * i0 + 1], g1 = Vp[2 * i1 + 1], g2 = Vp[2 * i2 + 1];
                float ax = r1.x - r0.x, ay = r1.y - r0.y, az = r1.z - r0.z;
                float bx = r2.x - r0.x, by = r2.y - r0.y, bz = r2.z - r0.z;
                atomicAdd(&vnr[3 * lv + 0], ay * bz - az * by);
                atomicAdd(&vnr[3 * lv + 1], az * bx - ax * bz);
                atomicAdd(&vnr[3 * lv + 2], ax * by - ay * bx);
                ax = g1.x - g0.x; ay = g1.y - g0.y; az = g1.z - g0.z;
                bx = g2.x - g0.x; by = g2.y - g0.y; bz = g2.z - g0.z;
                atomicAdd(&vng[3 * lv + 0], ay * bz - az * by);
                atomicAdd(&vng[3 * lv + 1], az * bx - ax * bz);
                atomicAdd(&vng[3 * lv + 2], ax * by - ay * bx);
            }
        }
    }
    __syncthreads();
    normals_epilogue(vnr, vng, accum, N, b0, g);
}

// ---- Laplacian accumulate ----

__device__ __forceinline__ void lap_accum_oct(
    const float4* __restrict__ Vp,
    const int2* __restrict__ rec, int n,
    float* dlr, float* dlg)
{
    int i = threadIdx.x;
    for (; i + 256 < n; i += 512) {
        int2 rc0 = rec[i], rc1 = rec[i + 256];
        int c0 = (unsigned)rc0.x >> BKSH, c1 = (unsigned)rc1.x >> BKSH;
        float4 pr0 = Vp[2 * c0], pg0 = Vp[2 * c0 + 1];
        float4 pr1 = Vp[2 * c1], pg1 = Vp[2 * c1 + 1];
        int lv0 = (unsigned)rc0.x & (BK - 1), lv1 = (unsigned)rc1.x & (BK - 1);
        float v0 = __int_as_float(rc0.y), v1 = __int_as_float(rc1.y);
        atomicAdd(&dlr[3 * lv0 + 0], v0 * pr0.x);
        atomicAdd(&dlr[3 * lv0 + 1], v0 * pr0.y);
        atomicAdd(&dlr[3 * lv0 + 2], v0 * pr0.z);
        atomicAdd(&dlg[3 * lv0 + 0], v0 * pg0.x);
        atomicAdd(&dlg[3 * lv0 + 1], v0 * pg0.y);
        atomicAdd(&dlg[3 * lv0 + 2], v0 * pg0.z);
        atomicAdd(&dlr[3 * lv1 + 0], v1 * pr1.x);
        atomicAdd(&dlr[3 * lv1 + 1], v1 * pr1.y);
        atomicAdd(&dlr[3 * lv1 + 2], v1 * pr1.z);
        atomicAdd(&dlg[3 * lv1 + 0], v1 * pg1.x);
        atomicAdd(&dlg[3 * lv1 + 1], v1 * pg1.y);
        atomicAdd(&dlg[3 * lv1 + 2], v1 * pg1.z);
    }
    for (; i < n; i += 256) {
        int2 rc = rec[i];
        unsigned u = (unsigned)rc.x;
        int lv  = u & (BK - 1);
        int col = u >> BKSH;
        float v = __int_as_float(rc.y);
        float4 pr = Vp[2 * col];
        float4 pg = Vp[2 * col + 1];
        atomicAdd(&dlr[3 * lv + 0], v * pr.x);
        atomicAdd(&dlr[3 * lv + 1], v * pr.y);
        atomicAdd(&dlr[3 * lv + 2], v * pr.z);
        atomicAdd(&dlg[3 * lv + 0], v * pg.x);
        atomicAdd(&dlg[3 * lv + 1], v * pg.y);
        atomicAdd(&dlg[3 * lv + 2], v * pg.z);
    }
}

__device__ __forceinline__ void lap_epilogue(
    const float* dlr, const float* dlg,
    float* accum, int N, int b0, int g)
{
    float vals2[2] = {0.f, 0.f};
    for (int lv = threadIdx.x; lv < BK; lv += blockDim.x) {
        int gv = ((b0 + g) << BKSH) + lv;
        if (gv < N) {
            float px = dlr[3 * lv], py = dlr[3 * lv + 1], pz = dlr[3 * lv + 2];
            float qx = dlg[3 * lv], qy = dlg[3 * lv + 1], qz = dlg[3 * lv + 2];
            bool fin = isfinite(px) && isfinite(py) && isfinite(pz) &&
                       isfinite(qx) && isfinite(qy) && isfinite(qz);
            vals2[1] += fin ? 0.f : 1.f;
            float dotl = px * qx + py * qy + pz * qz;
            float npn = sqrtf(px * px + py * py + pz * pz);
            float nqn = sqrtf(qx * qx + qy * qy + qz * qz);
            float cosl = dotl / (fmaxf(npn, COS_EPS_F) * fmaxf(nqn, COS_EPS_F));
            if (isnan(cosl)) cosl = 1.0f;
            vals2[0] += 1.0f - cosl;
        }
    }
    blockReduceAtomicN<2>(vals2, &accum[2]);
}

// Cooperative: grid-wide sync between col-octant windows (4 MB Vp each).
__global__ void __launch_bounds__(256) accum_lap_coop(
    const float4* __restrict__ Vp,
    const int* __restrict__ cntFine, const int2* __restrict__ recL, int capS,
    float* __restrict__ accum, int N, int b0)
{
    __shared__ float dlr[3 * BK];
    __shared__ float dlg[3 * BK];
    int g = blockIdx.x;
    for (int i = threadIdx.x; i < 3 * BK; i += blockDim.x) { dlr[i] = 0.f; dlg[i] = 0.f; }
    __syncthreads();
    for (int oct = 0; oct < NOCT; ++oct) {
        if (oct) cg::this_grid().sync();
        const int2* rec = recL + ((size_t)g * NOCT + oct) * capS;
        int n = min(cntFine[g * NOCT + oct], capS);
        lap_accum_oct(Vp, rec, n, dlr, dlg);
    }
    __syncthreads();
    lap_epilogue(dlr, dlg, accum, N, b0, g);
}

__global__ void __launch_bounds__(256) accum_lap_legacy(
    const float4* __restrict__ Vp,
    const int* __restrict__ cntFine, const int2* __restrict__ recL, int capS,
    float* __restrict__ accum, int N, int b0)
{
    __shared__ float dlr[3 * BK];
    __shared__ float dlg[3 * BK];
    int g = blockIdx.x;
    for (int i = threadIdx.x; i < 3 * BK; i += blockDim.x) { dlr[i] = 0.f; dlg[i] = 0.f; }
    __syncthreads();
    for (int oct = 0; oct < NOCT; ++oct) {
        const int2* rec = recL + ((size_t)g * NOCT + oct) * capS;
        int n = min(cntFine[g * NOCT + oct], capS);
        lap_accum_oct(Vp, rec, n, dlr, dlg);
    }
    __syncthreads();
    lap_epilogue(dlr, dlg, accum, N, b0, g);
}

__global__ void finalize_kernel(const float* __restrict__ accum,
                                float* __restrict__ out, int N)
{
    float invN = 1.0f / (float)N;
    float l1 = accum[0] * invN * (1.0f / 3.0f);
    float ln = accum[1] * invN;
    float ll = (accum[3] > 0.0f) ? 0.0f : accum[2] * invN;
    out[0] = 1.0f * l1 + 1.0f * ln + 0.1f * ll;
}

// ======================= FALLBACK PATH (round-1, known correct) =======================

__global__ void __launch_bounds__(256) face_normals_kernel(
    const float* __restrict__ Vr, const float* __restrict__ Vg,
    const int* __restrict__ faces,
    float* __restrict__ vn_rec, float* __restrict__ vn_gt, int F)
{
    int f = blockIdx.x * blockDim.x + threadIdx.x;
    if (f >= F) return;
    int i0 = faces[3 * f + 0], i1 = faces[3 * f + 1], i2 = faces[3 * f + 2];
    {
        float v0x = Vr[3 * i0], v0y = Vr[3 * i0 + 1], v0z = Vr[3 * i0 + 2];
        float v1x = Vr[3 * i1], v1y = Vr[3 * i1 + 1], v1z = Vr[3 * i1 + 2];
        float v2x = Vr[3 * i2], v2y = Vr[3 * i2 + 1], v2z = Vr[3 * i2 + 2];
        float ax = v1x - v0x, ay = v1y - v0y, az = v1z - v0z;
        float bx = v2x - v0x, by = v2y - v0y, bz = v2z - v0z;
        float nx = ay * bz - az * by, ny = az * bx - ax * bz, nz = ax * by - ay * bx;
        atomAddF(&vn_rec[3 * i0], nx); atomAddF(&vn_rec[3 * i0 + 1], ny); atomAddF(&vn_rec[3 * i0 + 2], nz);
        atomAddF(&vn_rec[3 * i1], nx); atomAddF(&vn_rec[3 * i1 + 1], ny); atomAddF(&vn_rec[3 * i1 + 2], nz);
        atomAddF(&vn_rec[3 * i2], nx); atomAddF(&vn_rec[3 * i2 + 1], ny); atomAddF(&vn_rec[3 * i2 + 2], nz);
    }
    {
        float v0x = Vg[3 * i0], v0y = Vg[3 * i0 + 1], v0z = Vg[3 * i0 + 2];
        float v1x = Vg[3 * i1], v1y = Vg[3 * i1 + 1], v1z = Vg[3 * i1 + 2];
        float v2x = Vg[3 * i2], v2y = Vg[3 * i2 + 1], v2z = Vg[3 * i2 + 2];
        float ax = v1x - v0x, ay = v1y - v0y, az = v1z - v0z;
        float bx = v2x - v0x, by = v2y - v0y, bz = v2z - v0z;
        float nx = ay * bz - az * by, ny = az * bx - ax * bz, nz = ax * by - ay * bx;
        atomAddF(&vn_gt[3 * i0], nx); atomAddF(&vn_gt[3 * i0 + 1], ny); atomAddF(&vn_gt[3 * i0 + 2], nz);
        atomAddF(&vn_gt[3 * i1], nx); atomAddF(&vn_gt[3 * i1 + 1], ny); atomAddF(&vn_gt[3 * i1 + 2], nz);
        atomAddF(&vn_gt[3 * i2], nx); atomAddF(&vn_gt[3 * i2 + 1], ny); atomAddF(&vn_gt[3 * i2 + 2], nz);
    }
}

__global__ void __launch_bounds__(256) spmm_kernel(
    const float* __restrict__ Vr, const float* __restrict__ Vg,
    const int* __restrict__ rows, const int* __restrict__ cols,
    const float* __restrict__ vals,
    float* __restrict__ dl_rec, float* __restrict__ dl_gt, int nnz)
{
    int i = blockIdx.x * blockDim.x + threadIdx.x;
    if (i >= nnz) return;
    int r = rows[i], c = cols[i];
    float v = vals[i];
    atomAddF(&dl_rec[3 * r], v * Vr[3 * c]);
    atomAddF(&dl_rec[3 * r + 1], v * Vr[3 * c + 1]);
    atomAddF(&dl_rec[3 * r + 2], v * Vr[3 * c + 2]);
    atomAddF(&dl_gt[3 * r], v * Vg[3 * c]);
    atomAddF(&dl_gt[3 * r + 1], v * Vg[3 * c + 1]);
    atomAddF(&dl_gt[3 * r + 2], v * Vg[3 * c + 2]);
}

__global__ void __launch_bounds__(256) reduce_kernel(
    const float* __restrict__ Vr, const float* __restrict__ Vg,
    const float* __restrict__ vn_rec, const float* __restrict__ vn_gt,
    const float* __restrict__ dl_rec, const float* __restrict__ dl_gt,
    float* __restrict__ accum, int N)
{
    int i = blockIdx.x * blockDim.x + threadIdx.x;
    float l1 = 0.0f, ln = 0.0f, ll = 0.0f, nonfin = 0.0f;
    if (i < N) {
        float rx = Vr[3 * i], ry = Vr[3 * i + 1], rz = Vr[3 * i + 2];
        float gx = Vg[3 * i], gy = Vg[3 * i + 1], gz = Vg[3 * i + 2];
        l1 = fabsf(rx - gx) + fabsf(ry - gy) + fabsf(rz - gz);
        float ax = vn_rec[3 * i], ay = vn_rec[3 * i + 1], az = vn_rec[3 * i + 2];
        float bx = vn_gt[3 * i],  by = vn_gt[3 * i + 1],  bz = vn_gt[3 * i + 2];
        float na = sqrtf(ax * ax + ay * ay + az * az);
        float nb = sqrtf(bx * bx + by * by + bz * bz);
        float ia = 1.0f / fmaxf(na, NORM_EPS_F);
        float ib = 1.0f / fmaxf(nb, NORM_EPS_F);
        ax *= ia; ay *= ia; az *= ia; bx *= ib; by *= ib; bz *= ib;
        float dot = ax * bx + ay * by + az * bz;
        float nna = sqrtf(ax * ax + ay * ay + az * az);
        float nnb = sqrtf(bx * bx + by * by + bz * bz);
        float cosn = dot / (fmaxf(nna, COS_EPS_F) * fmaxf(nnb, COS_EPS_F));
        if (isnan(cosn)) cosn = 1.0f;
        ln = 1.0f - cosn;
        float px = dl_rec[3 * i], py = dl_rec[3 * i + 1], pz = dl_rec[3 * i + 2];
        float qx = dl_gt[3 * i],  qy = dl_gt[3 * i + 1],  qz = dl_gt[3 * i + 2];
        bool fin = isfinite(px) && isfinite(py) && isfinite(pz) &&
                   isfinite(qx) && isfinite(qy) && isfinite(qz);
        nonfin = fin ? 0.0f : 1.0f;
        float dotl = px * qx + py * qy + pz * qz;
        float npn = sqrtf(px * px + py * py + pz * pz);
        float nqn = sqrtf(qx * qx + qy * qy + qz * qz);
        float cosl = dotl / (fmaxf(npn, COS_EPS_F) * fmaxf(nqn, COS_EPS_F));
        if (isnan(cosl)) cosl = 1.0f;
        ll = 1.0f - cosl;
    }
    float a[1] = {l1};  blockReduceAtomicN<1>(a, &accum[0]);
    float b[1] = {ln};  blockReduceAtomicN<1>(b, &accum[1]);
    float c2[2] = {ll, nonfin}; blockReduceAtomicN<2>(c2, &accum[2]);
}

// ======================= launch =======================

extern "C" void kernel_launch(void* const* d_in, const int* in_sizes, int n_in,
                              void* d_out, int out_size, void* d_ws, size_t ws_size,
                              hipStream_t stream)
{
    const float* Vr    = (const float*)d_in[0];
    const float* Vg    = (const float*)d_in[1];
    const int*   faces = (const int*)d_in[2];
    const int*   Lr    = (const int*)d_in[3];
    const int*   Lc    = (const int*)d_in[4];
    const float* Lv    = (const float*)d_in[5];

    const int N   = in_sizes[0] / 3;
    const int F   = in_sizes[2] / 3;
    const int NNZ = in_sizes[3];
    const int NB  = (N + BK - 1) >> BKSH;

    float* ws = (float*)d_ws;
    const int B = 256;

    // octant shifts (pure function of sizes)
    int lgN = 0; while ((1LL << lgN) < N) ++lgN;
    const int octsh = lgN > 3 ? lgN - 3 : 0;       // col octant = col >> octsh
    int lgF = 0; while ((1LL << lgF) < F) ++lgF;
    const int fsh = lgF > 3 ? lgF - 3 : 0;         // face octant = f >> fsh

    // ---- adaptive plan (pure function of sizes) ----
    const long long totW   = (long long)(ws_size / 4);
    const long long fixedW = 4 + 64 + (long long)NBGMAX * NOCT;  // accum, cntC, cntFine
    const long long vpW    = 8LL * N;
    const long long arenaW = totW - fixedW - vpW;
    const long long fnW    = 4LL * F;                            // fp16 FNH, 16 B/face

    const int capF  = 3 * F / (NB > 0 ? NB : 1) + 1 + 640;            // coarse-F per fine
    const int capL  = NNZ / (NB > 0 ? NB : 1) + 1 + 640;              // coarse-L per fine
    const int capFS = 3 * F / ((NB > 0 ? NB : 1) * NOCT) + 1 + 256;   // fine-F sub cap
    const int capS  = NNZ / ((NB > 0 ? NB : 1) * NOCT) + 1 + 256;     // fine-L sub cap

    auto fwords = [&](int nbg) -> long long {
        long long nc = (nbg + 31) / 32, capC = 32LL * capF;
        return nc * capC + (nc * capC + 3) / 4 + (long long)nbg * NOCT * capFS + 4;
    };
    auto lwords = [&](int nbg) -> long long {
        long long nc = (nbg + 31) / 32, capC = 32LL * capL;
        return nc * capC * 2 + (((nc * capC + 3) / 4 + 1) & ~1LL)
             + (long long)nbg * NOCT * capS * 2 + 4;
    };

    int NBG_F = NB < NBGMAX ? NB : NBGMAX;
    bool tierA = (arenaW - fnW) >= fwords(64);
    long long arenaF = tierA ? (arenaW - fnW) : arenaW;
    while (NBG_F > 64 && fwords(NBG_F) > arenaF) NBG_F -= 32;
    int NBG_L = NB < NBGMAX ? NB : NBGMAX;
    while (NBG_L > 64 && lwords(NBG_L) > arenaW) NBG_L -= 32;

    bool fast = (N <= (1 << 20)) && (F <= (1 << 22)) &&
                NBG_F >= 64 && NBG_L >= 64 &&
                fwords(NBG_F) <= arenaF && lwords(NBG_L) <= arenaW &&
                arenaW > 0;

    if (fast) {
        float*  accum   = ws;
        int*    cntC    = (int*)(ws + 4);
        int*    cntFine = (int*)(ws + 68);
        float4* Vp      = (float4*)(ws + fixedW);
        float*  arena   = ws + fixedW + vpW;

        // face-phase layout
        const long long NCF = (NBG_F + 31) / 32, capCF = 32LL * capF;
        uint4*         FNH   = (uint4*)arena;
        float*         fbase = tierA ? (arena + fnW) : arena;
        unsigned*      recAF = (unsigned*)fbase;
        unsigned char* recCF = (unsigned char*)(recAF + NCF * capCF);
        unsigned*      fineF = (unsigned*)(fbase + NCF * capCF + (NCF * capCF + 3) / 4);

        // L-phase layout (reuses the whole arena; runs after face phase)
        const long long NCL = (NBG_L + 31) / 32, capCL = 32LL * capL;
        int2*          recAL = (int2*)arena;
        unsigned char* recCL = (unsigned char*)(recAL + NCL * capCL);
        const long long bytesWL = ((NCL * capCL + 3) / 4 + 1) & ~1LL;
        int2*          fineL = (int2*)(arena + NCL * capCL * 2 + bytesWL);

        // cooperative co-residency check (capture-safe queries)
        int dev = 0; hipGetDevice(&dev);
        int numCU = 256;
        hipDeviceGetAttribute(&numCU, hipDeviceAttributeMultiprocessorCount, dev);
        int mbL = 0, mbN = 0;
        hipOccupancyMaxActiveBlocksPerMultiprocessor(&mbL, accum_lap_coop, 256, 0);
        hipOccupancyMaxActiveBlocksPerMultiprocessor(&mbN, accum_normals_coop, 256, 0);
        int bcntF0 = NB < NBG_F ? NB : NBG_F;
        int bcntL0 = NB < NBG_L ? NB : NBG_L;
        bool coopN = tierA && ((long long)mbN * numCU >= bcntF0);
        bool coopL = ((long long)mbL * numCU >= bcntL0);

        hipMemsetAsync(accum, 0, 4 * sizeof(float), stream);

        pack_l1_kernel<<<dim3((N + B - 1) / B), dim3(B), 0, stream>>>(Vr, Vg, Vp, accum, N);
        if (tierA) {
            int half = (F + 1) >> 1;
            fn_kernel<<<dim3((half + B - 1) / B), dim3(B), 0, stream>>>(Vp, faces, FNH, F);
        }

        int passF = (NB + NBG_F - 1) / NBG_F;
        for (int p = 0; p < passF; ++p) {
            int b0 = p * NBG_F;
            int bcnt = NB - b0 < NBG_F ? NB - b0 : NBG_F;
            int nc = (bcnt + 31) / 32;
            hipMemsetAsync(ws + 4, 0, (64 + (size_t)NBGMAX * NOCT) * sizeof(int), stream);
            bucket_F1<<<dim3((F + CHF1 - 1) / CHF1), dim3(B), 0, stream>>>(
                faces, cntC, recAF, recCF, (int)capCF, F, b0, bcnt, CHF1, fsh);
            bucket_F2<<<dim3(nc, K2), dim3(B), 0, stream>>>(
                cntC, recAF, recCF, (int)capCF, cntFine, fineF, capFS);
            if (coopN) {
                const uint4* FNHc = FNH; const int* cfc = cntFine;
                const unsigned* ffc = fineF; int capc = capFS;
                float* acc = accum; int Nc = N, b0c = b0;
                void* args[] = {&FNHc, &cfc, &ffc, &capc, &acc, &Nc, &b0c};
                hipLaunchCooperativeKernel((void*)accum_normals_coop,
                    dim3(bcnt), dim3(B), args, 0, stream);
            } else {
                accum_normals_legacy<<<dim3(bcnt), dim3(B), 0, stream>>>(
                    Vp, FNH, faces, cntFine, fineF, capFS, accum, N, b0, tierA ? 1 : 0);
            }
        }

        int passL = (NB + NBG_L - 1) / NBG_L;
        for (int p = 0; p < passL; ++p) {
            int b0 = p * NBG_L;
            int bcnt = NB - b0 < NBG_L ? NB - b0 : NBG_L;
            int nc = (bcnt + 31) / 32;
            hipMemsetAsync(ws + 4, 0, (64 + (size_t)NBGMAX * NOCT) * sizeof(int), stream);
            bucket_L1<<<dim3((NNZ + CHL1 - 1) / CHL1), dim3(B), 0, stream>>>(
                Lr, Lc, Lv, cntC, recAL, recCL, (int)capCL, NNZ, b0, bcnt, CHL1, octsh);
            bucket_L2<<<dim3(nc, K2), dim3(B), 0, stream>>>(
                cntC, recAL, recCL, (int)capCL, cntFine, fineL, capS);
            if (coopL) {
                const float4* Vpc = Vp; const int* cfc = cntFine;
                const int2* flc = fineL; int capc = capS;
                float* acc = accum; int Nc = N, b0c = b0;
                void* args[] = {&Vpc, &cfc, &flc, &capc, &acc, &Nc, &b0c};
                hipLaunchCooperativeKernel((void*)accum_lap_coop,
                    dim3(bcnt), dim3(B), args, 0, stream);
            } else {
                accum_lap_legacy<<<dim3(bcnt), dim3(B), 0, stream>>>(
                    Vp, cntFine, fineL, capS, accum, N, b0);
            }
        }
        finalize_kernel<<<dim3(1), dim3(1), 0, stream>>>(accum, (float*)d_out, N);
    } else {
        float* vn_rec = ws;
        float* vn_gt  = ws + (size_t)3 * N;
        float* dl_rec = ws + (size_t)6 * N;
        float* dl_gt  = ws + (size_t)9 * N;
        float* accum  = ws + (size_t)12 * N;
        hipMemsetAsync(d_ws, 0, ((size_t)12 * N + 4) * sizeof(float), stream);
        face_normals_kernel<<<dim3((F + B - 1) / B), dim3(B), 0, stream>>>(Vr, Vg, faces, vn_rec, vn_gt, F);
        spmm_kernel<<<dim3((NNZ + B - 1) / B), dim3(B), 0, stream>>>(Vr, Vg, Lr, Lc, Lv, dl_rec, dl_gt, NNZ);
        reduce_kernel<<<dim3((N + B - 1) / B), dim3(B), 0, stream>>>(Vr, Vg, vn_rec, vn_gt, dl_rec, dl_gt, accum, N);
        finalize_kernel<<<dim3(1), dim3(1), 0, stream>>>(accum, (float*)d_out, N);
    }
}

// Round 8
// 1393.903 us; speedup vs baseline: 2.9395x; 2.9395x over previous
//
#include <hip/hip_runtime.h>
#include <hip/hip_bf16.h>
#include <hip/hip_fp16.h>

#define NORM_EPS_F 1e-6f
#define COS_EPS_F  1e-8f
#define BK    512      // vertices per fine bucket
#define BKSH  9
#define CRSH  14       // coarse shift: 32 fine buckets per coarse
#define K2    32       // refine-stage chunks per coarse bucket
#define CH1   4096     // nnz per bucket_CL1 block
#define CHFS  2048     // faces per fn_scatter block

__device__ __forceinline__ void atomAddF(float* p, float v) {
    unsafeAtomicAdd(p, v);   // hardware global_atomic_add_f32
}

__device__ __forceinline__ unsigned packh2(float a, float b) {
    return (unsigned)__half_as_ushort(__float2half(a)) |
           ((unsigned)__half_as_ushort(__float2half(b)) << 16);
}
__device__ __forceinline__ float unpL(int u) {
    return __half2float(__ushort_as_half((unsigned short)((unsigned)u & 0xffff)));
}
__device__ __forceinline__ float unpH(int u) {
    return __half2float(__ushort_as_half((unsigned short)((unsigned)u >> 16)));
}

template<int NV>
__device__ __forceinline__ void blockReduceAtomicN(float (&v)[NV], float* dst) {
    #pragma unroll
    for (int off = 32; off > 0; off >>= 1) {
        #pragma unroll
        for (int k = 0; k < NV; ++k) v[k] += __shfl_down(v[k], off, 64);
    }
    __shared__ float red[4][NV];
    int wave = threadIdx.x >> 6, lane = threadIdx.x & 63;
    if (lane == 0) {
        #pragma unroll
        for (int k = 0; k < NV; ++k) red[wave][k] = v[k];
    }
    __syncthreads();
    if (threadIdx.x == 0) {
        float s[NV];
        #pragma unroll
        for (int k = 0; k < NV; ++k) s[k] = 0.f;
        for (int w = 0; w < 4; ++w)
            #pragma unroll
            for (int k = 0; k < NV; ++k) s[k] += red[w][k];
        #pragma unroll
        for (int k = 0; k < NV; ++k) atomAddF(&dst[k], s[k]);
    }
}

// ======================= FAST PATH =======================

__global__ void __launch_bounds__(256) pack_l1_kernel(
    const float* __restrict__ Vr, const float* __restrict__ Vg,
    float4* __restrict__ Vp, float* __restrict__ accum, int N)
{
    int i = blockIdx.x * blockDim.x + threadIdx.x;
    float l1[1] = {0.f};
    if (i < N) {
        float rx = Vr[3 * i], ry = Vr[3 * i + 1], rz = Vr[3 * i + 2];
        float gx = Vg[3 * i], gy = Vg[3 * i + 1], gz = Vg[3 * i + 2];
        Vp[2 * i]     = make_float4(rx, ry, rz, 0.f);
        Vp[2 * i + 1] = make_float4(gx, gy, gz, 0.f);
        l1[0] = fabsf(rx - gx) + fabsf(ry - gy) + fabsf(rz - gz);
    }
    blockReduceAtomicN<1>(l1, &accum[0]);
}

// ---- Laplacian stage 1: partition triplets by coarse col (64-way, 1KB+ runs) ----
__global__ void __launch_bounds__(256) bucket_CL1(
    const int* __restrict__ rows, const int* __restrict__ cols,
    const float* __restrict__ vals,
    int* __restrict__ cntC, int2* __restrict__ recA,
    unsigned short* __restrict__ recS, int capC, int nnz, int chunk)
{
    __shared__ int hist[64];
    int i0 = blockIdx.x * chunk, i1 = min(i0 + chunk, nnz);
    if (threadIdx.x < 64) hist[threadIdx.x] = 0;
    __syncthreads();
    for (int i = i0 + threadIdx.x; i < i1; i += 256)
        atomicAdd(&hist[(unsigned)cols[i] >> CRSH], 1);
    __syncthreads();
    if (threadIdx.x < 64) {
        int h = hist[threadIdx.x];
        if (h) hist[threadIdx.x] = atomicAdd(&cntC[threadIdx.x], h);
    }
    __syncthreads();
    for (int i = i0 + threadIdx.x; i < i1; i += 256) {
        unsigned c = (unsigned)cols[i];
        int cb = c >> CRSH;
        int pos = atomicAdd(&hist[cb], 1);
        if (pos < capC) {
            size_t idx = (size_t)cb * capC + pos;
            recA[idx] = make_int2(rows[i], __float_as_int(vals[i]));
            recS[idx] = (unsigned short)(c & ((1u << CRSH) - 1));  // fine5|low9
        }
    }
}

// ---- Laplacian stage 2: refine to (fine col, row-pass) stripes ----
__global__ void __launch_bounds__(256) bucket_CL2(
    const int* __restrict__ cntC, const int2* __restrict__ recA,
    const unsigned short* __restrict__ recS, int capC,
    int* __restrict__ cntS, int2* __restrict__ fineC, int capS,
    int RPSH, int NP)
{
    __shared__ int hist[256];
    int c = blockIdx.x;                   // coarse col bucket
    int k = blockIdx.y;
    int ch = (capC + K2 - 1) / K2;
    int n = min(cntC[c], capC);
    int i0 = k * ch, i1 = min(i0 + ch, n);
    hist[threadIdx.x] = 0;
    __syncthreads();
    const size_t base = (size_t)c * capC;
    for (int i = i0 + threadIdx.x; i < i1; i += 256) {
        int key = ((int)((unsigned)recA[base + i].x >> RPSH) << 5) |
                  ((unsigned)recS[base + i] >> 9);
        atomicAdd(&hist[key], 1);
    }
    __syncthreads();
    {
        int h = hist[threadIdx.x];
        if (h) {
            int s = (c * 32 + (threadIdx.x & 31)) * NP + (threadIdx.x >> 5);
            hist[threadIdx.x] = atomicAdd(&cntS[s], h);
        }
    }
    __syncthreads();
    for (int i = i0 + threadIdx.x; i < i1; i += 256) {
        int2 ra = recA[base + i];
        unsigned rs = recS[base + i];
        int key = ((int)((unsigned)ra.x >> RPSH) << 5) | (rs >> 9);
        int pos = atomicAdd(&hist[key], 1);
        if (pos < capS) {
            int s = (c * 32 + (key & 31)) * NP + (key >> 5);
            fineC[(size_t)s * capS + pos] =
                make_int2((ra.x << 9) | (int)(rs & 511), ra.y);
        }
    }
}

// ---- Laplacian product: LDS-staged V (sequential), fat fp16 product records ----
__global__ void __launch_bounds__(256) lap_product(
    const float4* __restrict__ Vp, const int* __restrict__ cntS,
    const int2* __restrict__ fineC, int capS, int NP, int pass,
    int* __restrict__ cntR, int4* __restrict__ fatR, int capRC,
    int cbase, int N)
{
    __shared__ float4 vld[2 * BK];       // 16 KB: this block's 512 verts, both meshes
    __shared__ int2   stash[1024];       // 8 KB record stash (single global read)
    __shared__ int    hist[64];
    int b = blockIdx.x;                  // fine col bucket
    int v0 = b << BKSH;
    int lim = min(2 * BK, 2 * (N - v0));
    for (int i = threadIdx.x; i < lim; i += 256)
        vld[i] = Vp[2 * (size_t)v0 + i];
    int s = b * NP + pass;
    int n = min(cntS[s], capS);
    const int2* rec = fineC + (size_t)s * capS;
    for (int s0 = 0; s0 < n; s0 += 1024) {
        int m = min(1024, n - s0);
        __syncthreads();
        if (threadIdx.x < 64) hist[threadIdx.x] = 0;
        for (int i = threadIdx.x; i < m; i += 256) stash[i] = rec[s0 + i];
        __syncthreads();
        for (int i = threadIdx.x; i < m; i += 256)
            atomicAdd(&hist[(((unsigned)stash[i].x >> 9) >> CRSH) - cbase], 1);
        __syncthreads();
        if (threadIdx.x < 64) {
            int h = hist[threadIdx.x];
            if (h) hist[threadIdx.x] = atomicAdd(&cntR[threadIdx.x], h);
        }
        __syncthreads();
        for (int i = threadIdx.x; i < m; i += 256) {
            int2 rc = stash[i];
            int row = (int)((unsigned)rc.x >> 9);
            int cl  = rc.x & (BK - 1);
            int lc  = (row >> CRSH) - cbase;
            int pos = atomicAdd(&hist[lc], 1);
            if (pos < capRC) {
                float v = __int_as_float(rc.y);
                float4 vr = vld[2 * cl];
                float4 vg = vld[2 * cl + 1];
                fatR[(size_t)lc * capRC + pos] = make_int4(
                    row,
                    (int)packh2(v * vr.x, v * vr.y),
                    (int)packh2(v * vr.z, v * vg.x),
                    (int)packh2(v * vg.y, v * vg.z));
            }
        }
    }
}

// ---- Generic fat-record refine: coarse (x>>14) -> fine (x>>9), local stripes ----
__global__ void __launch_bounds__(256) refine_fat(
    const int* __restrict__ cntIn, const int4* __restrict__ fatIn, int capIn,
    int* __restrict__ cntOut, int4* __restrict__ fatOut, int capOut)
{
    __shared__ int hist[32];
    int c = blockIdx.x;                  // local coarse
    int k = blockIdx.y;
    int ch = (capIn + K2 - 1) / K2;
    int n = min(cntIn[c], capIn);
    int i0 = k * ch, i1 = min(i0 + ch, n);
    if (threadIdx.x < 32) hist[threadIdx.x] = 0;
    __syncthreads();
    const size_t base = (size_t)c * capIn;
    for (int i = i0 + threadIdx.x; i < i1; i += 256)
        atomicAdd(&hist[((unsigned)fatIn[base + i].x >> BKSH) & 31], 1);
    __syncthreads();
    if (threadIdx.x < 32) {
        int h = hist[threadIdx.x];
        if (h) hist[threadIdx.x] = atomicAdd(&cntOut[c * 32 + threadIdx.x], h);
    }
    __syncthreads();
    for (int i = i0 + threadIdx.x; i < i1; i += 256) {
        int4 rc = fatIn[base + i];
        int j = ((unsigned)rc.x >> BKSH) & 31;
        int pos = atomicAdd(&hist[j], 1);
        if (pos < capOut)
            fatOut[(size_t)(c * 32 + j) * capOut + pos] = rc;
    }
}

// ---- Epilogues (verified numerics from prior rounds) ----

__device__ __forceinline__ void lap_epilogue(
    const float* dlr, const float* dlg, float* accum, int N, int b0, int g)
{
    float vals2[2] = {0.f, 0.f};
    for (int lv = threadIdx.x; lv < BK; lv += blockDim.x) {
        int gv = ((b0 + g) << BKSH) + lv;
        if (gv < N) {
            float px = dlr[3 * lv], py = dlr[3 * lv + 1], pz = dlr[3 * lv + 2];
            float qx = dlg[3 * lv], qy = dlg[3 * lv + 1], qz = dlg[3 * lv + 2];
            bool fin = isfinite(px) && isfinite(py) && isfinite(pz) &&
                       isfinite(qx) && isfinite(qy) && isfinite(qz);
            vals2[1] += fin ? 0.f : 1.f;
            float dotl = px * qx + py * qy + pz * qz;
            float npn = sqrtf(px * px + py * py + pz * pz);
            float nqn = sqrtf(qx * qx + qy * qy + qz * qz);
            float cosl = dotl / (fmaxf(npn, COS_EPS_F) * fmaxf(nqn, COS_EPS_F));
            if (isnan(cosl)) cosl = 1.0f;
            vals2[0] += 1.0f - cosl;
        }
    }
    blockReduceAtomicN<2>(vals2, &accum[2]);
}

__device__ __forceinline__ void normals_epilogue(
    const float* vnr, const float* vng, float* accum, int N, int b0, int g)
{
    float ln[1] = {0.f};
    for (int lv = threadIdx.x; lv < BK; lv += blockDim.x) {
        int gv = ((b0 + g) << BKSH) + lv;
        if (gv < N) {
            float ax = vnr[3 * lv], ay = vnr[3 * lv + 1], az = vnr[3 * lv + 2];
            float bx = vng[3 * lv], by = vng[3 * lv + 1], bz = vng[3 * lv + 2];
            float na = sqrtf(ax * ax + ay * ay + az * az);
            float nb = sqrtf(bx * bx + by * by + bz * bz);
            float ia = 1.0f / fmaxf(na, NORM_EPS_F);
            float ib = 1.0f / fmaxf(nb, NORM_EPS_F);
            ax *= ia; ay *= ia; az *= ia;
            bx *= ib; by *= ib; bz *= ib;
            float dot = ax * bx + ay * by + az * bz;
            float nna = sqrtf(ax * ax + ay * ay + az * az);
            float nnb = sqrtf(bx * bx + by * by + bz * bz);
            float cosn = dot / (fmaxf(nna, COS_EPS_F) * fmaxf(nnb, COS_EPS_F));
            if (isnan(cosn)) cosn = 1.0f;
            ln[0] += 1.0f - cosn;
        }
    }
    blockReduceAtomicN<1>(ln, &accum[1]);
}

// ---- Accumulate from sequential fat streams ----

__global__ void __launch_bounds__(256) accum_fat_lap(
    const int* __restrict__ cntW, const int4* __restrict__ fat, int capOut,
    float* __restrict__ accum, int N, int b0)
{
    __shared__ float dlr[3 * BK];
    __shared__ float dlg[3 * BK];
    int g = blockIdx.x;
    for (int i = threadIdx.x; i < 3 * BK; i += 256) { dlr[i] = 0.f; dlg[i] = 0.f; }
    __syncthreads();
    int n = min(cntW[g], capOut);
    const int4* rec = fat + (size_t)g * capOut;
    for (int i = threadIdx.x; i < n; i += 256) {
        int4 rc = rec[i];
        int lv = rc.x & (BK - 1);
        atomicAdd(&dlr[3 * lv + 0], unpL(rc.y));
        atomicAdd(&dlr[3 * lv + 1], unpH(rc.y));
        atomicAdd(&dlr[3 * lv + 2], unpL(rc.z));
        atomicAdd(&dlg[3 * lv + 0], unpH(rc.z));
        atomicAdd(&dlg[3 * lv + 1], unpL(rc.w));
        atomicAdd(&dlg[3 * lv + 2], unpH(rc.w));
    }
    __syncthreads();
    lap_epilogue(dlr, dlg, accum, N, b0, g);
}

__global__ void __launch_bounds__(256) accum_fat_norm(
    const int* __restrict__ cntW, const int4* __restrict__ fat, int capOut,
    float* __restrict__ accum, int N, int b0)
{
    __shared__ float vnr[3 * BK];
    __shared__ float vng[3 * BK];
    int g = blockIdx.x;
    for (int i = threadIdx.x; i < 3 * BK; i += 256) { vnr[i] = 0.f; vng[i] = 0.f; }
    __syncthreads();
    int n = min(cntW[g], capOut);
    const int4* rec = fat + (size_t)g * capOut;
    for (int i = threadIdx.x; i < n; i += 256) {
        int4 rc = rec[i];
        int lv = rc.x & (BK - 1);
        atomicAdd(&vnr[3 * lv + 0], unpL(rc.y));
        atomicAdd(&vnr[3 * lv + 1], unpH(rc.y));
        atomicAdd(&vnr[3 * lv + 2], unpL(rc.z));
        atomicAdd(&vng[3 * lv + 0], unpH(rc.z));
        atomicAdd(&vng[3 * lv + 1], unpL(rc.w));
        atomicAdd(&vng[3 * lv + 2], unpH(rc.w));
    }
    __syncthreads();
    normals_epilogue(vnr, vng, accum, N, b0, g);
}

// ---- Fused face-normal compute + corner scatter (fat fp16 normal records) ----
__global__ void __launch_bounds__(256) fn_scatter(
    const float4* __restrict__ Vp, const int* __restrict__ faces, int F,
    int* __restrict__ cntN, int4* __restrict__ fatN, int capNC)
{
    __shared__ unsigned stash[3 * CHFS];   // 24 KB: both normals fp16 per face
    __shared__ int hist[64];
    int f0 = blockIdx.x * CHFS;
    int f1 = min(f0 + CHFS, F);
    if (threadIdx.x < 64) hist[threadIdx.x] = 0;
    __syncthreads();
    // phase 1: gather verts (irreducible random), compute+stash normals, hist
    for (int f = f0 + threadIdx.x; f < f1; f += 512) {
        int fB = f + 256;
        bool hasB = fB < f1;
        int a0 = faces[3 * f], a1 = faces[3 * f + 1], a2 = faces[3 * f + 2];
        int c0 = 0, c1 = 0, c2 = 0;
        if (hasB) { c0 = faces[3 * fB]; c1 = faces[3 * fB + 1]; c2 = faces[3 * fB + 2]; }
        float4 ar0 = Vp[2 * a0], ag0 = Vp[2 * a0 + 1];
        float4 ar1 = Vp[2 * a1], ag1 = Vp[2 * a1 + 1];
        float4 ar2 = Vp[2 * a2], ag2 = Vp[2 * a2 + 1];
        float4 br0, bg0, br1, bg1, br2, bg2;
        if (hasB) {
            br0 = Vp[2 * c0]; bg0 = Vp[2 * c0 + 1];
            br1 = Vp[2 * c1]; bg1 = Vp[2 * c1 + 1];
            br2 = Vp[2 * c2]; bg2 = Vp[2 * c2 + 1];
        }
        {
            float ax = ar1.x - ar0.x, ay = ar1.y - ar0.y, az = ar1.z - ar0.z;
            float bx = ar2.x - ar0.x, by = ar2.y - ar0.y, bz = ar2.z - ar0.z;
            float nrx = ay * bz - az * by, nry = az * bx - ax * bz, nrz = ax * by - ay * bx;
            ax = ag1.x - ag0.x; ay = ag1.y - ag0.y; az = ag1.z - ag0.z;
            bx = ag2.x - ag0.x; by = ag2.y - ag0.y; bz = ag2.z - ag0.z;
            float ngx = ay * bz - az * by, ngy = az * bx - ax * bz, ngz = ax * by - ay * bx;
            int li = f - f0;
            stash[3 * li]     = packh2(nrx, nry);
            stash[3 * li + 1] = packh2(nrz, ngx);
            stash[3 * li + 2] = packh2(ngy, ngz);
            atomicAdd(&hist[(unsigned)a0 >> CRSH], 1);
            atomicAdd(&hist[(unsigned)a1 >> CRSH], 1);
            atomicAdd(&hist[(unsigned)a2 >> CRSH], 1);
        }
        if (hasB) {
            float ax = br1.x - br0.x, ay = br1.y - br0.y, az = br1.z - br0.z;
            float bx = br2.x - br0.x, by = br2.y - br0.y, bz = br2.z - br0.z;
            float nrx = ay * bz - az * by, nry = az * bx - ax * bz, nrz = ax * by - ay * bx;
            ax = bg1.x - bg0.x; ay = bg1.y - bg0.y; az = bg1.z - bg0.z;
            bx = bg2.x - bg0.x; by = bg2.y - bg0.y; bz = bg2.z - bg0.z;
            float ngx = ay * bz - az * by, ngy = az * bx - ax * bz, ngz = ax * by - ay * bx;
            int li = fB - f0;
            stash[3 * li]     = packh2(nrx, nry);
            stash[3 * li + 1] = packh2(nrz, ngx);
            stash[3 * li + 2] = packh2(ngy, ngz);
            atomicAdd(&hist[(unsigned)c0 >> CRSH], 1);
            atomicAdd(&hist[(unsigned)c1 >> CRSH], 1);
            atomicAdd(&hist[(unsigned)c2 >> CRSH], 1);
        }
    }
    __syncthreads();
    if (threadIdx.x < 64) {
        int h = hist[threadIdx.x];
        if (h) hist[threadIdx.x] = atomicAdd(&cntN[threadIdx.x], h);
    }
    __syncthreads();
    // phase 2: scatter records (faces re-read are L1/L2-hot)
    for (int f = f0 + threadIdx.x; f < f1; f += 256) {
        int li = f - f0;
        int s0 = (int)stash[3 * li], s1 = (int)stash[3 * li + 1], s2 = (int)stash[3 * li + 2];
        #pragma unroll
        for (int c = 0; c < 3; ++c) {
            int v = faces[3 * f + c];
            int cb = (unsigned)v >> CRSH;
            int pos = atomicAdd(&hist[cb], 1);
            if (pos < capNC)
                fatN[(size_t)cb * capNC + pos] = make_int4(v, s0, s1, s2);
        }
    }
}

__global__ void finalize_kernel(const float* __restrict__ accum,
                                float* __restrict__ out, int N)
{
    float invN = 1.0f / (float)N;
    float l1 = accum[0] * invN * (1.0f / 3.0f);
    float ln = accum[1] * invN;
    float ll = (accum[3] > 0.0f) ? 0.0f : accum[2] * invN;
    out[0] = 1.0f * l1 + 1.0f * ln + 0.1f * ll;
}

// ======================= FALLBACK PATH (round-1, known correct) =======================

__global__ void __launch_bounds__(256) face_normals_kernel(
    const float* __restrict__ Vr, const float* __restrict__ Vg,
    const int* __restrict__ faces,
    float* __restrict__ vn_rec, float* __restrict__ vn_gt, int F)
{
    int f = blockIdx.x * blockDim.x + threadIdx.x;
    if (f >= F) return;
    int i0 = faces[3 * f + 0], i1 = faces[3 * f + 1], i2 = faces[3 * f + 2];
    {
        float v0x = Vr[3 * i0], v0y = Vr[3 * i0 + 1], v0z = Vr[3 * i0 + 2];
        float v1x = Vr[3 * i1], v1y = Vr[3 * i1 + 1], v1z = Vr[3 * i1 + 2];
        float v2x = Vr[3 * i2], v2y = Vr[3 * i2 + 1], v2z = Vr[3 * i2 + 2];
        float ax = v1x - v0x, ay = v1y - v0y, az = v1z - v0z;
        float bx = v2x - v0x, by = v2y - v0y, bz = v2z - v0z;
        float nx = ay * bz - az * by, ny = az * bx - ax * bz, nz = ax * by - ay * bx;
        atomAddF(&vn_rec[3 * i0], nx); atomAddF(&vn_rec[3 * i0 + 1], ny); atomAddF(&vn_rec[3 * i0 + 2], nz);
        atomAddF(&vn_rec[3 * i1], nx); atomAddF(&vn_rec[3 * i1 + 1], ny); atomAddF(&vn_rec[3 * i1 + 2], nz);
        atomAddF(&vn_rec[3 * i2], nx); atomAddF(&vn_rec[3 * i2 + 1], ny); atomAddF(&vn_rec[3 * i2 + 2], nz);
    }
    {
        float v0x = Vg[3 * i0], v0y = Vg[3 * i0 + 1], v0z = Vg[3 * i0 + 2];
        float v1x = Vg[3 * i1], v1y = Vg[3 * i1 + 1], v1z = Vg[3 * i1 + 2];
        float v2x = Vg[3 * i2], v2y = Vg[3 * i2 + 1], v2z = Vg[3 * i2 + 2];
        float ax = v1x - v0x, ay = v1y - v0y, az = v1z - v0z;
        float bx = v2x - v0x, by = v2y - v0y, bz = v2z - v0z;
        float nx = ay * bz - az * by, ny = az * bx - ax * bz, nz = ax * by - ay * bx;
        atomAddF(&vn_gt[3 * i0], nx); atomAddF(&vn_gt[3 * i0 + 1], ny); atomAddF(&vn_gt[3 * i0 + 2], nz);
        atomAddF(&vn_gt[3 * i1], nx); atomAddF(&vn_gt[3 * i1 + 1], ny); atomAddF(&vn_gt[3 * i1 + 2], nz);
        atomAddF(&vn_gt[3 * i2], nx); atomAddF(&vn_gt[3 * i2 + 1], ny); atomAddF(&vn_gt[3 * i2 + 2], nz);
    }
}

__global__ void __launch_bounds__(256) spmm_kernel(
    const float* __restrict__ Vr, const float* __restrict__ Vg,
    const int* __restrict__ rows, const int* __restrict__ cols,
    const float* __restrict__ vals,
    float* __restrict__ dl_rec, float* __restrict__ dl_gt, int nnz)
{
    int i = blockIdx.x * blockDim.x + threadIdx.x;
    if (i >= nnz) return;
    int r = rows[i], c = cols[i];
    float v = vals[i];
    atomAddF(&dl_rec[3 * r], v * Vr[3 * c]);
    atomAddF(&dl_rec[3 * r + 1], v * Vr[3 * c + 1]);
    atomAddF(&dl_rec[3 * r + 2], v * Vr[3 * c + 2]);
    atomAddF(&dl_gt[3 * r], v * Vg[3 * c]);
    atomAddF(&dl_gt[3 * r + 1], v * Vg[3 * c + 1]);
    atomAddF(&dl_gt[3 * r + 2], v * Vg[3 * c + 2]);
}

__global__ void __launch_bounds__(256) reduce_kernel(
    const float* __restrict__ Vr, const float* __restrict__ Vg,
    const float* __restrict__ vn_rec, const float* __restrict__ vn_gt,
    const float* __restrict__ dl_rec, const float* __restrict__ dl_gt,
    float* __restrict__ accum, int N)
{
    int i = blockIdx.x * blockDim.x + threadIdx.x;
    float l1 = 0.0f, ln = 0.0f, ll = 0.0f, nonfin = 0.0f;
    if (i < N) {
        float rx = Vr[3 * i], ry = Vr[3 * i + 1], rz = Vr[3 * i + 2];
        float gx = Vg[3 * i], gy = Vg[3 * i + 1], gz = Vg[3 * i + 2];
        l1 = fabsf(rx - gx) + fabsf(ry - gy) + fabsf(rz - gz);
        float ax = vn_rec[3 * i], ay = vn_rec[3 * i + 1], az = vn_rec[3 * i + 2];
        float bx = vn_gt[3 * i],  by = vn_gt[3 * i + 1],  bz = vn_gt[3 * i + 2];
        float na = sqrtf(ax * ax + ay * ay + az * az);
        float nb = sqrtf(bx * bx + by * by + bz * bz);
        float ia = 1.0f / fmaxf(na, NORM_EPS_F);
        float ib = 1.0f / fmaxf(nb, NORM_EPS_F);
        ax *= ia; ay *= ia; az *= ia; bx *= ib; by *= ib; bz *= ib;
        float dot = ax * bx + ay * by + az * bz;
        float nna = sqrtf(ax * ax + ay * ay + az * az);
        float nnb = sqrtf(bx * bx + by * by + bz * bz);
        float cosn = dot / (fmaxf(nna, COS_EPS_F) * fmaxf(nnb, COS_EPS_F));
        if (isnan(cosn)) cosn = 1.0f;
        ln = 1.0f - cosn;
        float px = dl_rec[3 * i], py = dl_rec[3 * i + 1], pz = dl_rec[3 * i + 2];
        float qx = dl_gt[3 * i],  qy = dl_gt[3 * i + 1],  qz = dl_gt[3 * i + 2];
        bool fin = isfinite(px) && isfinite(py) && isfinite(pz) &&
                   isfinite(qx) && isfinite(qy) && isfinite(qz);
        nonfin = fin ? 0.0f : 1.0f;
        float dotl = px * qx + py * qy + pz * qz;
        float npn = sqrtf(px * px + py * py + pz * pz);
        float nqn = sqrtf(qx * qx + qy * qy + qz * qz);
        float cosl = dotl / (fmaxf(npn, COS_EPS_F) * fmaxf(nqn, COS_EPS_F));
        if (isnan(cosl)) cosl = 1.0f;
        ll = 1.0f - cosl;
    }
    float a[1] = {l1};  blockReduceAtomicN<1>(a, &accum[0]);
    float b[1] = {ln};  blockReduceAtomicN<1>(b, &accum[1]);
    float c2[2] = {ll, nonfin}; blockReduceAtomicN<2>(c2, &accum[2]);
}

// ======================= launch =======================

extern "C" void kernel_launch(void* const* d_in, const int* in_sizes, int n_in,
                              void* d_out, int out_size, void* d_ws, size_t ws_size,
                              hipStream_t stream)
{
    const float* Vr    = (const float*)d_in[0];
    const float* Vg    = (const float*)d_in[1];
    const int*   faces = (const int*)d_in[2];
    const int*   Lr    = (const int*)d_in[3];
    const int*   Lc    = (const int*)d_in[4];
    const float* Lv    = (const float*)d_in[5];

    const int N   = in_sizes[0] / 3;
    const int F   = in_sizes[2] / 3;
    const int NNZ = in_sizes[3];
    const int NBF = (N + BK - 1) >> BKSH;       // fine buckets
    const int NCC = (NBF + 31) >> 5;            // coarse buckets (<=64)

    float* ws = (float*)d_ws;
    const int B = 256;

    // ---- adaptive plan (pure function of sizes -> graph-safe) ----
    const long long totW   = (long long)(ws_size / 4);
    const long long fixedW = 4 + 64 + 2048 + 16384;    // accum|cnt64|cntW|cntS
    const long long vpW    = 8LL * N;

    const long long capC  = NNZ / 64 + NNZ / 1024 + 512;
    const long long Xw    = 64 * capC * 2 + (64 * capC + 1) / 2;  // recA + recS
    const long long capRC = NNZ / 64 + NNZ / 512 + 1024;
    const long long capRS = NNZ / (NBF > 0 ? NBF : 1) + NNZ / (8LL * (NBF > 0 ? NBF : 1)) + 256;
    const long long capNC = 3LL * F / 64 + 3LL * F / 512 + 1024;
    const long long NRw   = 64 * capNC * 4;
    const long long capNS = 3LL * F / (NBF > 0 ? NBF : 1) + 3LL * F / (8LL * (NBF > 0 ? NBF : 1)) + 256;

    int bppL = 0, bppN = 0;
    long long capSL = 0;
    long long arena = 0;
    // candidates: fewer passes preferred
    const int cand[4] = {2048, 1024, 512, 256};
    for (int li = 0; li < 4 && bppL == 0; ++li) {
        int bl = cand[li];
        int np = (NBF + bl - 1) / bl;
        if (np > 8) continue;
        long long cS = NNZ / ((long long)NBF * np) + NNZ / (4LL * NBF * np) + 128;
        long long Yw = (long long)NBF * np * cS * 2;
        long long Zw = (long long)(bl >> 5) * capRC * 4;
        long long Ww = (long long)bl * capRS * 4;
        long long lapA = Xw + Yw + Zw + (Ww <= Xw ? 0 : Ww);
        for (int ni = 0; ni < 4; ++ni) {
            int bn = cand[ni];
            long long NFw = (long long)bn * capNS * 4;
            long long normA = NRw + NFw;
            long long ar = lapA > normA ? lapA : normA;
            if (fixedW + vpW + ar <= totW) {
                bppL = bl; bppN = bn; capSL = cS; arena = ar;
                break;
            }
        }
    }

    bool fast = (N <= (1 << 20)) && (F <= (1 << 22)) && NBF >= 64 && bppL > 0;

    if (fast) {
        const int NP  = (NBF + bppL - 1) / bppL;
        const int NPn = (NBF + bppN - 1) / bppN;
        int RPSH = BKSH;
        { int t = bppL; while (t > 1) { t >>= 1; ++RPSH; } }   // 9 + log2(bppL)

        float* accum  = ws;
        int*   cnt64  = (int*)(ws + 4);
        int*   cntW   = (int*)(ws + 68);
        int*   cntS   = (int*)(ws + 2116);
        float4* Vp    = (float4*)(ws + fixedW);
        float* arenaP = ws + fixedW + vpW;

        // lap layout
        long long cS = capSL;
        long long Yw = (long long)NBF * NP * cS * 2;
        long long Zw = (long long)(bppL >> 5) * capRC * 4;
        long long Ww = (long long)bppL * capRS * 4;
        int2*           recA  = (int2*)arenaP;
        unsigned short* recS  = (unsigned short*)(arenaP + 64 * capC * 2);
        int2*           fineC = (int2*)(arenaP + Xw);
        int4*           fatR  = (int4*)(arenaP + Xw + Yw);
        int4*           fatW  = (Ww <= Xw) ? (int4*)arenaP : (int4*)(arenaP + Xw + Yw + Zw);
        // normals layout (lap buffers dead by then)
        int4*           fatNR = (int4*)arenaP;
        int4*           fatNF = (int4*)(arenaP + NRw);

        // zero accum + all counters once
        hipMemsetAsync(ws, 0, fixedW * sizeof(float), stream);

        pack_l1_kernel<<<dim3((N + B - 1) / B), dim3(B), 0, stream>>>(Vr, Vg, Vp, accum, N);

        // ---- LAPLACIAN ----
        bucket_CL1<<<dim3((NNZ + CH1 - 1) / CH1), dim3(B), 0, stream>>>(
            Lr, Lc, Lv, cnt64, recA, recS, (int)capC, NNZ, CH1);
        bucket_CL2<<<dim3(NCC, K2), dim3(B), 0, stream>>>(
            cnt64, recA, recS, (int)capC, cntS, fineC, (int)cS, RPSH, NP);
        for (int p = 0; p < NP; ++p) {
            int cbase = p * (bppL >> 5);
            int nCPp = NCC - cbase; if (nCPp > (bppL >> 5)) nCPp = bppL >> 5;
            if (nCPp <= 0) break;
            int bcnt = NBF - p * bppL; if (bcnt > bppL) bcnt = bppL;
            hipMemsetAsync(ws + 4, 0, 2112 * sizeof(int), stream);   // cnt64 + cntW
            lap_product<<<dim3(NBF), dim3(B), 0, stream>>>(
                Vp, cntS, fineC, (int)cS, NP, p, cnt64, fatR, (int)capRC, cbase, N);
            refine_fat<<<dim3(nCPp, K2), dim3(B), 0, stream>>>(
                cnt64, fatR, (int)capRC, cntW, fatW, (int)capRS);
            accum_fat_lap<<<dim3(bcnt), dim3(B), 0, stream>>>(
                cntW, fatW, (int)capRS, accum, N, p * bppL);
        }

        // ---- NORMALS ----
        hipMemsetAsync(ws + 4, 0, 2112 * sizeof(int), stream);       // cnt64 + cntW
        fn_scatter<<<dim3((F + CHFS - 1) / CHFS), dim3(B), 0, stream>>>(
            Vp, faces, F, cnt64, fatNR, (int)capNC);
        for (int p = 0; p < NPn; ++p) {
            int cbase = p * (bppN >> 5);
            int nCPn = NCC - cbase; if (nCPn > (bppN >> 5)) nCPn = bppN >> 5;
            if (nCPn <= 0) break;
            int bcnt = NBF - p * bppN; if (bcnt > bppN) bcnt = bppN;
            if (p > 0) hipMemsetAsync(ws + 68, 0, 2048 * sizeof(int), stream);  // cntW only
            refine_fat<<<dim3(nCPn, K2), dim3(B), 0, stream>>>(
                cnt64 + cbase, fatNR + (size_t)cbase * capNC, (int)capNC,
                cntW, fatNF, (int)capNS);
            accum_fat_norm<<<dim3(bcnt), dim3(B), 0, stream>>>(
                cntW, fatNF, (int)capNS, accum, N, p * bppN);
        }
        finalize_kernel<<<dim3(1), dim3(1), 0, stream>>>(accum, (float*)d_out, N);
    } else {
        float* vn_rec = ws;
        float* vn_gt  = ws + (size_t)3 * N;
        float* dl_rec = ws + (size_t)6 * N;
        float* dl_gt  = ws + (size_t)9 * N;
        float* accum  = ws + (size_t)12 * N;
        hipMemsetAsync(d_ws, 0, ((size_t)12 * N + 4) * sizeof(float), stream);
        face_normals_kernel<<<dim3((F + B - 1) / B), dim3(B), 0, stream>>>(Vr, Vg, faces, vn_rec, vn_gt, F);
        spmm_kernel<<<dim3((NNZ + B - 1) / B), dim3(B), 0, stream>>>(Vr, Vg, Lr, Lc, Lv, dl_rec, dl_gt, NNZ);
        reduce_kernel<<<dim3((N + B - 1) / B), dim3(B), 0, stream>>>(Vr, Vg, vn_rec, vn_gt, dl_rec, dl_gt, accum, N);
        finalize_kernel<<<dim3(1), dim3(1), 0, stream>>>(accum, (float*)d_out, N);
    }
}

// Round 10
// 1248.844 us; speedup vs baseline: 3.2810x; 1.1162x over previous
//
#include <hip/hip_runtime.h>
#include <hip/hip_bf16.h>
#include <hip/hip_fp16.h>

#define NORM_EPS_F 1e-6f
#define COS_EPS_F  1e-8f
#define BK    512      // cols per fine col-bucket (lap LDS staging)
#define BKSH  9
#define CRSH  14       // coarse col shift (64-way CL1)
#define VBSH  12       // accumulate bucket: 4096 verts/rows per block
#define K2    32
#define CH1   4096     // nnz per bucket_CL1 block
#define CHFS  2048     // faces per fn_scatter block

__device__ __forceinline__ void atomAddF(float* p, float v) {
    unsafeAtomicAdd(p, v);   // hardware global_atomic_add_f32
}

__device__ __forceinline__ unsigned packh2(float a, float b) {
    return (unsigned)__half_as_ushort(__float2half(a)) |
           ((unsigned)__half_as_ushort(__float2half(b)) << 16);
}

// Packed half2 LDS atomic add: prefer HW pk_add_f16 via unsafeAtomicAdd
// overload; SFINAE falls back to a CAS loop if the overload is absent.
template <typename P>
__device__ __forceinline__ auto h2add_impl(P* p, __half2 v, int)
    -> decltype((void)unsafeAtomicAdd(p, v)) {
    unsafeAtomicAdd(p, v);
}
template <typename P>
__device__ __forceinline__ void h2add_impl(P* p, __half2 v, long) {
    unsigned* up = (unsigned*)p;
    unsigned old = *up;
    while (true) {
        __half2 cur = *(__half2*)&old;
        __half2 s = __hadd2(cur, v);
        unsigned nv = *(unsigned*)&s;
        unsigned prev = atomicCAS(up, old, nv);
        if (prev == old) break;
        old = prev;
    }
}
__device__ __forceinline__ void h2add(__half2* p, __half2 v) { h2add_impl(p, v, 0); }

template<int NV>
__device__ __forceinline__ void blockReduceAtomicN(float (&v)[NV], float* dst) {
    #pragma unroll
    for (int off = 32; off > 0; off >>= 1) {
        #pragma unroll
        for (int k = 0; k < NV; ++k) v[k] += __shfl_down(v[k], off, 64);
    }
    __shared__ float red[4][NV];
    int wave = threadIdx.x >> 6, lane = threadIdx.x & 63;
    if (lane == 0) {
        #pragma unroll
        for (int k = 0; k < NV; ++k) red[wave][k] = v[k];
    }
    __syncthreads();
    if (threadIdx.x == 0) {
        float s[NV];
        #pragma unroll
        for (int k = 0; k < NV; ++k) s[k] = 0.f;
        for (int w = 0; w < 4; ++w)
            #pragma unroll
            for (int k = 0; k < NV; ++k) s[k] += red[w][k];
        #pragma unroll
        for (int k = 0; k < NV; ++k) atomAddF(&dst[k], s[k]);
    }
}

// ======================= FAST PATH =======================

__global__ void __launch_bounds__(256) pack_l1_kernel(
    const float* __restrict__ Vr, const float* __restrict__ Vg,
    float4* __restrict__ Vp, float* __restrict__ accum, int N)
{
    int i = blockIdx.x * blockDim.x + threadIdx.x;
    float l1[1] = {0.f};
    if (i < N) {
        float rx = Vr[3 * i], ry = Vr[3 * i + 1], rz = Vr[3 * i + 2];
        float gx = Vg[3 * i], gy = Vg[3 * i + 1], gz = Vg[3 * i + 2];
        Vp[2 * i]     = make_float4(rx, ry, rz, 0.f);
        Vp[2 * i + 1] = make_float4(gx, gy, gz, 0.f);
        l1[0] = fabsf(rx - gx) + fabsf(ry - gy) + fabsf(rz - gz);
    }
    blockReduceAtomicN<1>(l1, &accum[0]);
}

// ---- Lap stage 1: partition triplets by coarse col (64-way, >=1KB runs) ----
__global__ void __launch_bounds__(256) bucket_CL1(
    const int* __restrict__ rows, const int* __restrict__ cols,
    const float* __restrict__ vals,
    int* __restrict__ cntC, int2* __restrict__ recA,
    unsigned short* __restrict__ recS, int capC, int nnz, int chunk)
{
    __shared__ int hist[64];
    int i0 = blockIdx.x * chunk, i1 = min(i0 + chunk, nnz);
    if (threadIdx.x < 64) hist[threadIdx.x] = 0;
    __syncthreads();
    for (int i = i0 + threadIdx.x; i < i1; i += 256)
        atomicAdd(&hist[(unsigned)cols[i] >> CRSH], 1);
    __syncthreads();
    if (threadIdx.x < 64) {
        int h = hist[threadIdx.x];
        if (h) hist[threadIdx.x] = atomicAdd(&cntC[threadIdx.x], h);
    }
    __syncthreads();
    for (int i = i0 + threadIdx.x; i < i1; i += 256) {
        unsigned c = (unsigned)cols[i];
        int cb = c >> CRSH;
        int pos = atomicAdd(&hist[cb], 1);
        if (pos < capC) {
            size_t idx = (size_t)cb * capC + pos;
            recA[idx] = make_int2(rows[i], __float_as_int(vals[i]));
            recS[idx] = (unsigned short)(c & ((1u << CRSH) - 1));  // fine5|low9
        }
    }
}

// ---- Lap stage 2: refine to fine col buckets (records = (row<<9)|colLow, val) ----
__global__ void __launch_bounds__(256) bucket_CL2(
    const int* __restrict__ cntC, const int2* __restrict__ recA,
    const unsigned short* __restrict__ recS, int capC,
    int* __restrict__ cntS, int2* __restrict__ fineC, int capS)
{
    __shared__ int hist[32];
    int c = blockIdx.x;
    int k = blockIdx.y;
    int ch = (capC + K2 - 1) / K2;
    int n = min(cntC[c], capC);
    int i0 = k * ch, i1 = min(i0 + ch, n);
    if (threadIdx.x < 32) hist[threadIdx.x] = 0;
    __syncthreads();
    const size_t base = (size_t)c * capC;
    for (int i = i0 + threadIdx.x; i < i1; i += 256)
        atomicAdd(&hist[(unsigned)recS[base + i] >> 9], 1);
    __syncthreads();
    if (threadIdx.x < 32) {
        int h = hist[threadIdx.x];
        if (h) hist[threadIdx.x] = atomicAdd(&cntS[c * 32 + threadIdx.x], h);
    }
    __syncthreads();
    for (int i = i0 + threadIdx.x; i < i1; i += 256) {
        int2 ra = recA[base + i];
        unsigned rs = recS[base + i];
        int fine = rs >> 9;
        int pos = atomicAdd(&hist[fine], 1);
        if (pos < capS)
            fineC[(size_t)(c * 32 + fine) * capS + pos] =
                make_int2((ra.x << 9) | (int)(rs & 511), ra.y);
    }
}

// ---- Lap product: LDS-staged V window, fat fp16 pair records scattered by
//      4K-row accumulate bucket; pass-filtered to rows [b0p<<12, (b0p+nbp)<<12). ----
__global__ void __launch_bounds__(256) lap_product2(
    const float4* __restrict__ Vp, const int* __restrict__ cntS,
    const int2* __restrict__ fineC, int capS,
    int* __restrict__ cntL, int4* __restrict__ fatL, int capLC, int N,
    int b0p, int nbp)
{
    __shared__ float4 vld[2 * BK];       // 16 KB
    __shared__ int2   stash[2048];       // 16 KB
    __shared__ int    hist[256];
    int b = blockIdx.x;
    int v0 = b << BKSH;
    int lim = min(2 * BK, 2 * (N - v0));
    for (int i = threadIdx.x; i < lim; i += 256)
        vld[i] = Vp[2 * (size_t)v0 + i];
    int n = min(cntS[b], capS);
    const int2* rec = fineC + (size_t)b * capS;
    for (int s0 = 0; s0 < n; s0 += 2048) {
        int m = min(2048, n - s0);
        __syncthreads();
        hist[threadIdx.x] = 0;
        for (int i = threadIdx.x; i < m; i += 256) stash[i] = rec[s0 + i];
        __syncthreads();
        for (int i = threadIdx.x; i < m; i += 256) {
            unsigned cb = (((unsigned)stash[i].x >> 9) >> VBSH) - (unsigned)b0p;
            if (cb < (unsigned)nbp) atomicAdd(&hist[cb], 1);
        }
        __syncthreads();
        {
            int h = hist[threadIdx.x];
            if (h) hist[threadIdx.x] = atomicAdd(&cntL[threadIdx.x], h);
        }
        __syncthreads();
        for (int i = threadIdx.x; i < m; i += 256) {
            int2 rc = stash[i];
            int row = (int)((unsigned)rc.x >> 9);
            unsigned cb = ((unsigned)row >> VBSH) - (unsigned)b0p;
            if (cb < (unsigned)nbp) {
                int pos = atomicAdd(&hist[cb], 1);
                if (pos < capLC) {
                    int cl = rc.x & 511;
                    float v = __int_as_float(rc.y);
                    float4 vr = vld[2 * cl];
                    float4 vg = vld[2 * cl + 1];
                    fatL[(size_t)cb * capLC + pos] = make_int4(
                        row,
                        (int)packh2(v * vr.x, v * vg.x),
                        (int)packh2(v * vr.y, v * vg.y),
                        (int)packh2(v * vr.z, v * vg.z));
                }
            }
        }
    }
}

// ---- Accumulate lap: 4096-row bucket per block, packed half2 LDS atomics ----
__global__ void __launch_bounds__(256) accum_lap_direct(
    const int* __restrict__ cntL, const int4* __restrict__ fatL, int capLC,
    float* __restrict__ accum, int N, int b0)
{
    __shared__ __half2 dl[3 * 4096];     // 48 KB: (rec_c, gt_c) per coordinate
    int g = blockIdx.x;
    {
        int* z = (int*)dl;
        for (int i = threadIdx.x; i < 3 * 4096; i += 256) z[i] = 0;
    }
    __syncthreads();
    int n = min(cntL[g], capLC);
    const int4* rec = fatL + (size_t)g * capLC;
    for (int i = threadIdx.x; i < n; i += 256) {
        int4 rc = rec[i];
        int lv = rc.x & 4095;
        h2add(&dl[3 * lv + 0], *(__half2*)&rc.y);
        h2add(&dl[3 * lv + 1], *(__half2*)&rc.z);
        h2add(&dl[3 * lv + 2], *(__half2*)&rc.w);
    }
    __syncthreads();
    float vals2[2] = {0.f, 0.f};
    for (int lv = threadIdx.x; lv < 4096; lv += 256) {
        int gv = ((b0 + g) << VBSH) + lv;
        if (gv < N) {
            float2 x = __half22float2(dl[3 * lv + 0]);
            float2 y = __half22float2(dl[3 * lv + 1]);
            float2 z = __half22float2(dl[3 * lv + 2]);
            float px = x.x, py = y.x, pz = z.x;   // rec
            float qx = x.y, qy = y.y, qz = z.y;   // gt
            bool fin = isfinite(px) && isfinite(py) && isfinite(pz) &&
                       isfinite(qx) && isfinite(qy) && isfinite(qz);
            vals2[1] += fin ? 0.f : 1.f;
            float dotl = px * qx + py * qy + pz * qz;
            float npn = sqrtf(px * px + py * py + pz * pz);
            float nqn = sqrtf(qx * qx + qy * qy + qz * qz);
            float cosl = dotl / (fmaxf(npn, COS_EPS_F) * fmaxf(nqn, COS_EPS_F));
            if (isnan(cosl)) cosl = 1.0f;
            vals2[0] += 1.0f - cosl;
        }
    }
    blockReduceAtomicN<2>(vals2, &accum[2]);
}

// ---- Fused face-normal compute + corner scatter by 4K-vert bucket ----
__global__ void __launch_bounds__(256) fn_scatter2(
    const float4* __restrict__ Vp, const int* __restrict__ faces, int F,
    int* __restrict__ cntN, int4* __restrict__ fatN, int capNC)
{
    __shared__ unsigned stash[3 * CHFS];   // 24 KB: per-coordinate (nr,ng) fp16 pairs
    __shared__ int hist[256];
    int f0 = blockIdx.x * CHFS;
    int f1 = min(f0 + CHFS, F);
    hist[threadIdx.x] = 0;
    __syncthreads();
    for (int f = f0 + threadIdx.x; f < f1; f += 512) {
        int fB = f + 256;
        bool hasB = fB < f1;
        int a0 = faces[3 * f], a1 = faces[3 * f + 1], a2 = faces[3 * f + 2];
        int c0 = 0, c1 = 0, c2 = 0;
        if (hasB) { c0 = faces[3 * fB]; c1 = faces[3 * fB + 1]; c2 = faces[3 * fB + 2]; }
        float4 ar0 = Vp[2 * a0], ag0 = Vp[2 * a0 + 1];
        float4 ar1 = Vp[2 * a1], ag1 = Vp[2 * a1 + 1];
        float4 ar2 = Vp[2 * a2], ag2 = Vp[2 * a2 + 1];
        float4 br0, bg0, br1, bg1, br2, bg2;
        if (hasB) {
            br0 = Vp[2 * c0]; bg0 = Vp[2 * c0 + 1];
            br1 = Vp[2 * c1]; bg1 = Vp[2 * c1 + 1];
            br2 = Vp[2 * c2]; bg2 = Vp[2 * c2 + 1];
        }
        {
            float ax = ar1.x - ar0.x, ay = ar1.y - ar0.y, az = ar1.z - ar0.z;
            float bx = ar2.x - ar0.x, by = ar2.y - ar0.y, bz = ar2.z - ar0.z;
            float nrx = ay * bz - az * by, nry = az * bx - ax * bz, nrz = ax * by - ay * bx;
            ax = ag1.x - ag0.x; ay = ag1.y - ag0.y; az = ag1.z - ag0.z;
            bx = ag2.x - ag0.x; by = ag2.y - ag0.y; bz = ag2.z - ag0.z;
            float ngx = ay * bz - az * by, ngy = az * bx - ax * bz, ngz = ax * by - ay * bx;
            int li = f - f0;
            stash[3 * li]     = packh2(nrx, ngx);
            stash[3 * li + 1] = packh2(nry, ngy);
            stash[3 * li + 2] = packh2(nrz, ngz);
            atomicAdd(&hist[(unsigned)a0 >> VBSH], 1);
            atomicAdd(&hist[(unsigned)a1 >> VBSH], 1);
            atomicAdd(&hist[(unsigned)a2 >> VBSH], 1);
        }
        if (hasB) {
            float ax = br1.x - br0.x, ay = br1.y - br0.y, az = br1.z - br0.z;
            float bx = br2.x - br0.x, by = br2.y - br0.y, bz = br2.z - br0.z;
            float nrx = ay * bz - az * by, nry = az * bx - ax * bz, nrz = ax * by - ay * bx;
            ax = bg1.x - bg0.x; ay = bg1.y - bg0.y; az = bg1.z - bg0.z;
            bx = bg2.x - bg0.x; by = bg2.y - bg0.y; bz = bg2.z - bg0.z;
            float ngx = ay * bz - az * by, ngy = az * bx - ax * bz, ngz = ax * by - ay * bx;
            int li = fB - f0;
            stash[3 * li]     = packh2(nrx, ngx);
            stash[3 * li + 1] = packh2(nry, ngy);
            stash[3 * li + 2] = packh2(nrz, ngz);
            atomicAdd(&hist[(unsigned)c0 >> VBSH], 1);
            atomicAdd(&hist[(unsigned)c1 >> VBSH], 1);
            atomicAdd(&hist[(unsigned)c2 >> VBSH], 1);
        }
    }
    __syncthreads();
    {
        int h = hist[threadIdx.x];
        if (h) hist[threadIdx.x] = atomicAdd(&cntN[threadIdx.x], h);
    }
    __syncthreads();
    for (int f = f0 + threadIdx.x; f < f1; f += 256) {
        int li = f - f0;
        int s0 = (int)stash[3 * li], s1 = (int)stash[3 * li + 1], s2 = (int)stash[3 * li + 2];
        #pragma unroll
        for (int c = 0; c < 3; ++c) {
            int v = faces[3 * f + c];
            int cb = (unsigned)v >> VBSH;
            int pos = atomicAdd(&hist[cb], 1);
            if (pos < capNC)
                fatN[(size_t)cb * capNC + pos] = make_int4(v, s0, s1, s2);
        }
    }
}

// ---- Accumulate normals: same packed-half2 pattern ----
__global__ void __launch_bounds__(256) accum_norm_direct(
    const int* __restrict__ cntN, const int4* __restrict__ fatN, int capNC,
    float* __restrict__ accum, int N)
{
    __shared__ __half2 vn[3 * 4096];     // 48 KB
    int g = blockIdx.x;
    {
        int* z = (int*)vn;
        for (int i = threadIdx.x; i < 3 * 4096; i += 256) z[i] = 0;
    }
    __syncthreads();
    int n = min(cntN[g], capNC);
    const int4* rec = fatN + (size_t)g * capNC;
    for (int i = threadIdx.x; i < n; i += 256) {
        int4 rc = rec[i];
        int lv = rc.x & 4095;
        h2add(&vn[3 * lv + 0], *(__half2*)&rc.y);
        h2add(&vn[3 * lv + 1], *(__half2*)&rc.z);
        h2add(&vn[3 * lv + 2], *(__half2*)&rc.w);
    }
    __syncthreads();
    float ln[1] = {0.f};
    for (int lv = threadIdx.x; lv < 4096; lv += 256) {
        int gv = (g << VBSH) + lv;
        if (gv < N) {
            float2 x = __half22float2(vn[3 * lv + 0]);
            float2 y = __half22float2(vn[3 * lv + 1]);
            float2 z = __half22float2(vn[3 * lv + 2]);
            float ax = x.x, ay = y.x, az = z.x;
            float bx = x.y, by = y.y, bz = z.y;
            float na = sqrtf(ax * ax + ay * ay + az * az);
            float nb = sqrtf(bx * bx + by * by + bz * bz);
            float ia = 1.0f / fmaxf(na, NORM_EPS_F);
            float ib = 1.0f / fmaxf(nb, NORM_EPS_F);
            ax *= ia; ay *= ia; az *= ia;
            bx *= ib; by *= ib; bz *= ib;
            float dot = ax * bx + ay * by + az * bz;
            float nna = sqrtf(ax * ax + ay * ay + az * az);
            float nnb = sqrtf(bx * bx + by * by + bz * bz);
            float cosn = dot / (fmaxf(nna, COS_EPS_F) * fmaxf(nnb, COS_EPS_F));
            if (isnan(cosn)) cosn = 1.0f;
            ln[0] += 1.0f - cosn;
        }
    }
    blockReduceAtomicN<1>(ln, &accum[1]);
}

__global__ void finalize_kernel(const float* __restrict__ accum,
                                float* __restrict__ out, int N)
{
    float invN = 1.0f / (float)N;
    float l1 = accum[0] * invN * (1.0f / 3.0f);
    float ln = accum[1] * invN;
    float ll = (accum[3] > 0.0f) ? 0.0f : accum[2] * invN;
    out[0] = 1.0f * l1 + 1.0f * ln + 0.1f * ll;
}

// ======================= FALLBACK PATH (round-1, known correct) =======================

__global__ void __launch_bounds__(256) face_normals_kernel(
    const float* __restrict__ Vr, const float* __restrict__ Vg,
    const int* __restrict__ faces,
    float* __restrict__ vn_rec, float* __restrict__ vn_gt, int F)
{
    int f = blockIdx.x * blockDim.x + threadIdx.x;
    if (f >= F) return;
    int i0 = faces[3 * f + 0], i1 = faces[3 * f + 1], i2 = faces[3 * f + 2];
    {
        float v0x = Vr[3 * i0], v0y = Vr[3 * i0 + 1], v0z = Vr[3 * i0 + 2];
        float v1x = Vr[3 * i1], v1y = Vr[3 * i1 + 1], v1z = Vr[3 * i1 + 2];
        float v2x = Vr[3 * i2], v2y = Vr[3 * i2 + 1], v2z = Vr[3 * i2 + 2];
        float ax = v1x - v0x, ay = v1y - v0y, az = v1z - v0z;
        float bx = v2x - v0x, by = v2y - v0y, bz = v2z - v0z;
        float nx = ay * bz - az * by, ny = az * bx - ax * bz, nz = ax * by - ay * bx;
        atomAddF(&vn_rec[3 * i0], nx); atomAddF(&vn_rec[3 * i0 + 1], ny); atomAddF(&vn_rec[3 * i0 + 2], nz);
        atomAddF(&vn_rec[3 * i1], nx); atomAddF(&vn_rec[3 * i1 + 1], ny); atomAddF(&vn_rec[3 * i1 + 2], nz);
        atomAddF(&vn_rec[3 * i2], nx); atomAddF(&vn_rec[3 * i2 + 1], ny); atomAddF(&vn_rec[3 * i2 + 2], nz);
    }
    {
        float v0x = Vg[3 * i0], v0y = Vg[3 * i0 + 1], v0z = Vg[3 * i0 + 2];
        float v1x = Vg[3 * i1], v1y = Vg[3 * i1 + 1], v1z = Vg[3 * i1 + 2];
        float v2x = Vg[3 * i2], v2y = Vg[3 * i2 + 1], v2z = Vg[3 * i2 + 2];
        float ax = v1x - v0x, ay = v1y - v0y, az = v1z - v0z;
        float bx = v2x - v0x, by = v2y - v0y, bz = v2z - v0z;
        float nx = ay * bz - az * by, ny = az * bx - ax * bz, nz = ax * by - ay * bx;
        atomAddF(&vn_gt[3 * i0], nx); atomAddF(&vn_gt[3 * i0 + 1], ny); atomAddF(&vn_gt[3 * i0 + 2], nz);
        atomAddF(&vn_gt[3 * i1], nx); atomAddF(&vn_gt[3 * i1 + 1], ny); atomAddF(&vn_gt[3 * i1 + 2], nz);
        atomAddF(&vn_gt[3 * i2], nx); atomAddF(&vn_gt[3 * i2 + 1], ny); atomAddF(&vn_gt[3 * i2 + 2], nz);
    }
}

__global__ void __launch_bounds__(256) spmm_kernel(
    const float* __restrict__ Vr, const float* __restrict__ Vg,
    const int* __restrict__ rows, const int* __restrict__ cols,
    const float* __restrict__ vals,
    float* __restrict__ dl_rec, float* __restrict__ dl_gt, int nnz)
{
    int i = blockIdx.x * blockDim.x + threadIdx.x;
    if (i >= nnz) return;
    int r = rows[i], c = cols[i];
    float v = vals[i];
    atomAddF(&dl_rec[3 * r], v * Vr[3 * c]);
    atomAddF(&dl_rec[3 * r + 1], v * Vr[3 * c + 1]);
    atomAddF(&dl_rec[3 * r + 2], v * Vr[3 * c + 2]);
    atomAddF(&dl_gt[3 * r], v * Vg[3 * c]);
    atomAddF(&dl_gt[3 * r + 1], v * Vg[3 * c + 1]);
    atomAddF(&dl_gt[3 * r + 2], v * Vg[3 * c + 2]);
}

__global__ void __launch_bounds__(256) reduce_kernel(
    const float* __restrict__ Vr, const float* __restrict__ Vg,
    const float* __restrict__ vn_rec, const float* __restrict__ vn_gt,
    const float* __restrict__ dl_rec, const float* __restrict__ dl_gt,
    float* __restrict__ accum, int N)
{
    int i = blockIdx.x * blockDim.x + threadIdx.x;
    float l1 = 0.0f, ln = 0.0f, ll = 0.0f, nonfin = 0.0f;
    if (i < N) {
        float rx = Vr[3 * i], ry = Vr[3 * i + 1], rz = Vr[3 * i + 2];
        float gx = Vg[3 * i], gy = Vg[3 * i + 1], gz = Vg[3 * i + 2];
        l1 = fabsf(rx - gx) + fabsf(ry - gy) + fabsf(rz - gz);
        float ax = vn_rec[3 * i], ay = vn_rec[3 * i + 1], az = vn_rec[3 * i + 2];
        float bx = vn_gt[3 * i],  by = vn_gt[3 * i + 1],  bz = vn_gt[3 * i + 2];
        float na = sqrtf(ax * ax + ay * ay + az * az);
        float nb = sqrtf(bx * bx + by * by + bz * bz);
        float ia = 1.0f / fmaxf(na, NORM_EPS_F);
        float ib = 1.0f / fmaxf(nb, NORM_EPS_F);
        ax *= ia; ay *= ia; az *= ia; bx *= ib; by *= ib; bz *= ib;
        float dot = ax * bx + ay * by + az * bz;
        float nna = sqrtf(ax * ax + ay * ay + az * az);
        float nnb = sqrtf(bx * bx + by * by + bz * bz);
        float cosn = dot / (fmaxf(nna, COS_EPS_F) * fmaxf(nnb, COS_EPS_F));
        if (isnan(cosn)) cosn = 1.0f;
        ln = 1.0f - cosn;
        float px = dl_rec[3 * i], py = dl_rec[3 * i + 1], pz = dl_rec[3 * i + 2];
        float qx = dl_gt[3 * i],  qy = dl_gt[3 * i + 1],  qz = dl_gt[3 * i + 2];
        bool fin = isfinite(px) && isfinite(py) && isfinite(pz) &&
                   isfinite(qx) && isfinite(qy) && isfinite(qz);
        nonfin = fin ? 0.0f : 1.0f;
        float dotl = px * qx + py * qy + pz * qz;
        float npn = sqrtf(px * px + py * py + pz * pz);
        float nqn = sqrtf(qx * qx + qy * qy + qz * qz);
        float cosl = dotl / (fmaxf(npn, COS_EPS_F) * fmaxf(nqn, COS_EPS_F));
        if (isnan(cosl)) cosl = 1.0f;
        ll = 1.0f - cosl;
    }
    float a[1] = {l1};  blockReduceAtomicN<1>(a, &accum[0]);
    float b[1] = {ln};  blockReduceAtomicN<1>(b, &accum[1]);
    float c2[2] = {ll, nonfin}; blockReduceAtomicN<2>(c2, &accum[2]);
}

// ======================= launch =======================

extern "C" void kernel_launch(void* const* d_in, const int* in_sizes, int n_in,
                              void* d_out, int out_size, void* d_ws, size_t ws_size,
                              hipStream_t stream)
{
    const float* Vr    = (const float*)d_in[0];
    const float* Vg    = (const float*)d_in[1];
    const int*   faces = (const int*)d_in[2];
    const int*   Lr    = (const int*)d_in[3];
    const int*   Lc    = (const int*)d_in[4];
    const float* Lv    = (const float*)d_in[5];

    const int N   = in_sizes[0] / 3;
    const int F   = in_sizes[2] / 3;
    const int NNZ = in_sizes[3];
    const int NBF = (N + BK - 1) >> BKSH;        // fine col buckets (<=2048)
    const int NCC = (NBF + 31) >> 5;             // coarse col buckets (<=64)
    const int NCB = (N + 4095) >> VBSH;          // accumulate buckets (<=256)

    float* ws = (float*)d_ws;
    const int B = 256;

    // ---- adaptive plan (pure function of sizes -> graph-safe) ----
    const long long totW   = (long long)(ws_size / 4);
    const long long fixedW = 4 + 64 + 2048 + 256 + 256;   // accum|cntC|cntS|cntL|cntN

    const long long capC   = NNZ / 64 + NNZ / 1024 + 512;
    const int       capS   = NNZ / (NBF > 0 ? NBF : 1) + NNZ / (4 * (NBF > 0 ? NBF : 1)) + 128;
    const long long capLC  = NNZ / (NCB > 0 ? NCB : 1) + NNZ / (4LL * (NCB > 0 ? NCB : 1)) + 2048;
    const long long capNC2 = 3LL * F / (NCB > 0 ? NCB : 1) + 3LL * F / (4LL * (NCB > 0 ? NCB : 1)) + 2048;

    const long long recAw  = 64 * capC * 2;
    const long long recSw  = (64 * capC + 1) / 2;
    const long long fineCw = 2048LL * capS * 2;
    const long long fatNw  = (long long)NCB * capNC2 * 4;

    // choose pass count NPL so the arena fits: fatL overlays recA/recS region
    int NPL = 0, NCBP = 0;
    long long arenaW = 0;
    const int npcand[4] = {1, 2, 4, 8};
    for (int i = 0; i < 4; ++i) {
        int np = npcand[i];
        int ncbp = (NCB + np - 1) / np;
        long long fatLw = (long long)ncbp * capLC * 4;
        long long r2w = (recAw + recSw) > fatLw ? (recAw + recSw) : fatLw;
        long long aw = fineCw + r2w;
        if (fatNw > aw) aw = fatNw;
        if (fixedW + 8LL * N + aw <= totW) { NPL = np; NCBP = ncbp; arenaW = aw; break; }
    }

    bool fast = (N <= (1 << 20)) && (F <= (1 << 22)) &&
                NBF >= 64 && NCB >= 2 && NCB <= 256 && NPL > 0;

    if (fast) {
        float*  accum = ws;
        int*    cntC  = (int*)(ws + 4);
        int*    cntS  = (int*)(ws + 68);
        int*    cntL  = (int*)(ws + 2116);
        int*    cntN  = (int*)(ws + 2372);
        float4* Vp    = (float4*)(ws + fixedW);
        float*  arena = ws + fixedW + 8LL * N;

        int2*           fineC = (int2*)arena;
        int2*           recA  = (int2*)(arena + fineCw);
        unsigned short* recS  = (unsigned short*)(arena + fineCw + recAw);
        int4*           fatL  = (int4*)(arena + fineCw);   // overlays recA/recS
        int4*           fatN  = (int4*)arena;              // overlays all lap buffers

        hipMemsetAsync(ws, 0, fixedW * sizeof(float), stream);   // accum + all counters

        pack_l1_kernel<<<dim3((N + B - 1) / B), dim3(B), 0, stream>>>(Vr, Vg, Vp, accum, N);

        // ---- LAPLACIAN ----
        bucket_CL1<<<dim3((NNZ + CH1 - 1) / CH1), dim3(B), 0, stream>>>(
            Lr, Lc, Lv, cntC, recA, recS, (int)capC, NNZ, CH1);
        bucket_CL2<<<dim3(NCC, K2), dim3(B), 0, stream>>>(
            cntC, recA, recS, (int)capC, cntS, fineC, capS);
        for (int p = 0; p < NPL; ++p) {
            int b0 = p * NCBP;
            int nb = NCB - b0; if (nb > NCBP) nb = NCBP;
            if (nb <= 0) break;
            if (p > 0) hipMemsetAsync(cntL, 0, 256 * sizeof(int), stream);
            lap_product2<<<dim3(NBF), dim3(B), 0, stream>>>(
                Vp, cntS, fineC, capS, cntL, fatL, (int)capLC, N, b0, nb);
            accum_lap_direct<<<dim3(nb), dim3(B), 0, stream>>>(
                cntL, fatL, (int)capLC, accum, N, b0);
        }

        // ---- NORMALS (fatN overlays lap arena; lap fully consumed above) ----
        fn_scatter2<<<dim3((F + CHFS - 1) / CHFS), dim3(B), 0, stream>>>(
            Vp, faces, F, cntN, fatN, (int)capNC2);
        accum_norm_direct<<<dim3(NCB), dim3(B), 0, stream>>>(
            cntN, fatN, (int)capNC2, accum, N);

        finalize_kernel<<<dim3(1), dim3(1), 0, stream>>>(accum, (float*)d_out, N);
    } else {
        float* vn_rec = ws;
        float* vn_gt  = ws + (size_t)3 * N;
        float* dl_rec = ws + (size_t)6 * N;
        float* dl_gt  = ws + (size_t)9 * N;
        float* accum  = ws + (size_t)12 * N;
        hipMemsetAsync(d_ws, 0, ((size_t)12 * N + 4) * sizeof(float), stream);
        face_normals_kernel<<<dim3((F + B - 1) / B), dim3(B), 0, stream>>>(Vr, Vg, faces, vn_rec, vn_gt, F);
        spmm_kernel<<<dim3((NNZ + B - 1) / B), dim3(B), 0, stream>>>(Vr, Vg, Lr, Lc, Lv, dl_rec, dl_gt, NNZ);
        reduce_kernel<<<dim3((N + B - 1) / B), dim3(B), 0, stream>>>(Vr, Vg, vn_rec, vn_gt, dl_rec, dl_gt, accum, N);
        finalize_kernel<<<dim3(1), dim3(1), 0, stream>>>(accum, (float*)d_out, N);
    }
}